// Round 9
// baseline (489.817 us; speedup 1.0000x reference)
//
#include <hip/hip_runtime.h>
#include <hip/hip_bf16.h>
#include <math.h>

#define N_NODES 2048
#define C_NODES 256
#define BATCH   64
#define UNITS   64
#define JS      4096                // state-part columns: j = b*64+u
#define NX      4160                // + 64 input-channel columns
#define JSX     4224                // padded to 33 x 128 tiles (66 x 64-blocks)
#define NU      131072              // N_NODES * UNITS
#define XSTR    4160                // X row stride (state cols + input cols)
#define CAP     192                 // max nnz per adj row (mean ~33)
#define ZSPLIT  8                   // gemm1 split-K factor

typedef short  s16x8 __attribute__((ext_vector_type(8)));   // 8 bf16 in 4 VGPRs
typedef float  f32x4 __attribute__((ext_vector_type(4)));

__device__ __forceinline__ float sigmoidf_(float x) { return 1.0f / (1.0f + __expf(-x)); }

__device__ __forceinline__ float bfs2f(short s) {
    union { float f; unsigned u; } w; w.u = ((unsigned)(unsigned short)s) << 16; return w.f;
}
__device__ __forceinline__ short f2bfs(float f) {
    __hip_bfloat16 h = __float2bfloat16(f);
    short s; __builtin_memcpy(&s, &h, 2); return s;
}

__device__ __forceinline__ void gload_lds16(const void* g, void* l) {
    __builtin_amdgcn_global_load_lds(
        (const __attribute__((address_space(1))) void*)g,
        (__attribute__((address_space(3))) void*)l, 16, 0, 0);
}

// ---------------- converts ----------------
__global__ __launch_bounds__(256) void cvt_split(const float* __restrict__ s,
                                                 __hip_bfloat16* __restrict__ dh,
                                                 __hip_bfloat16* __restrict__ dl, int n)
{
    int stride = gridDim.x * 256;
    for (int i = blockIdx.x * 256 + threadIdx.x; i < n; i += stride) {
        float v = s[i];
        __hip_bfloat16 h = __float2bfloat16(v);
        dh[i] = h;
        dl[i] = __float2bfloat16(v - __bfloat162float(h));
    }
}

// w0[65][128], w1[65][64] -> blocked transposed bf16 h/l: cell (c*O+o), elem jj = w[(1+c*8+jj)*O + o]
__global__ __launch_bounds__(256) void cvt_w(const float* __restrict__ w0,
                                             const float* __restrict__ w1,
                                             __hip_bfloat16* __restrict__ w0h, __hip_bfloat16* __restrict__ w0l,
                                             __hip_bfloat16* __restrict__ w1h, __hip_bfloat16* __restrict__ w1l)
{
    int stride = gridDim.x * 256;
    for (int e = blockIdx.x * 256 + threadIdx.x; e < 8192 + 4096; e += stride) {
        if (e < 8192) {  // w0T: O=128
            int jj = e & 7, cell = e >> 3;
            int o = cell & 127, c = cell >> 7;
            float v = w0[(size_t)(1 + c * 8 + jj) * 128 + o];
            __hip_bfloat16 h = __float2bfloat16(v);
            w0h[e] = h; w0l[e] = __float2bfloat16(v - __bfloat162float(h));
        } else {         // w1T: O=64
            int e2 = e - 8192;
            int jj = e2 & 7, cell = e2 >> 3;
            int o = cell & 63, c = cell >> 6;
            float v = w1[(size_t)(1 + c * 8 + jj) * 64 + o];
            __hip_bfloat16 h = __float2bfloat16(v);
            w1h[e2] = h; w1l[e2] = __float2bfloat16(v - __bfloat162float(h));
        }
    }
}

// once: x0sT rows 4096..4159 = inputs (hi/lo); X input cols; zero rows 4160..4223 of x0sT/x0fcT
__global__ __launch_bounds__(256) void setup_ext(
    const float* __restrict__ inputs,
    __hip_bfloat16* __restrict__ xh, __hip_bfloat16* __restrict__ xl,
    __hip_bfloat16* __restrict__ fh, __hip_bfloat16* __restrict__ fl,
    __hip_bfloat16* __restrict__ X)
{
    int blk = blockIdx.x;
    if (blk < 64) {
        int b = blk;
        for (int n = threadIdx.x; n < N_NODES; n += 256) {
            float v = inputs[(size_t)b * N_NODES + n];
            __hip_bfloat16 h = __float2bfloat16(v);
            size_t o = (size_t)(JS + b) * N_NODES + n;
            xh[o] = h;
            xl[o] = __float2bfloat16(v - __bfloat162float(h));
            X[(size_t)n * XSTR + 4096 + b] = h;   // input cols of X (once; never rewritten)
        }
    } else {
        int r = NX + (blk - 64);   // 4160..4223
        __hip_bfloat16 z = __float2bfloat16(0.0f);
        for (int n = threadIdx.x; n < N_NODES; n += 256) {
            size_t o = (size_t)r * N_NODES + n;
            xh[o] = z; xl[o] = z;
        }
        for (int c = threadIdx.x; c < C_NODES; c += 256) {
            size_t o = (size_t)r * C_NODES + c;
            fh[o] = z; fl[o] = z;
        }
    }
}

// ---------------- adj -> CSR (once). One wave per row, ballot compaction ----------------
__global__ __launch_bounds__(256) void build_csr(
    const float* __restrict__ adj,
    unsigned short* __restrict__ cols,
    float* __restrict__ vals,
    int* __restrict__ nnz)
{
    int row  = blockIdx.x * 4 + (threadIdx.x >> 6);
    int lane = threadIdx.x & 63;
    const float* a = adj + (size_t)row * N_NODES;
    int base = 0;
    for (int k0 = 0; k0 < N_NODES; k0 += 64) {
        float v = a[k0 + lane];
        unsigned long long m = __ballot(v != 0.0f);
        if (v != 0.0f) {
            int pos = base + __popcll(m & ((1ull << lane) - 1));
            if (pos < CAP) {
                cols[(size_t)row * CAP + pos] = (unsigned short)(k0 + lane);
                vals[(size_t)row * CAP + pos] = v;
            }
        }
        base += __popcll(m);
    }
    if (lane == 0) nnz[row] = base < CAP ? base : CAP;
}

// pass-1 x0sT build: state[b][n*64+u] -> x0sT_h/l[(b*64+u)][n]; also X[n][b*64+u] = bf16(state)
__global__ __launch_bounds__(256) void build_x0sT(const float* __restrict__ st,
                                                  __hip_bfloat16* __restrict__ xh,
                                                  __hip_bfloat16* __restrict__ xl,
                                                  __hip_bfloat16* __restrict__ X)
{
    __shared__ float Ls[64 * 65];
    int n0 = blockIdx.x * 64;
    int b  = blockIdx.y;
    int t  = threadIdx.x;
    #pragma unroll
    for (int it = 0; it < 16; it++) {
        int idx = t + it * 256;
        int i = idx >> 6, u = idx & 63;
        float v = st[(size_t)b * NU + (size_t)(n0 + i) * 64 + u];
        Ls[i * 65 + u] = v;
        X[(size_t)(n0 + i) * XSTR + b * 64 + u] = __float2bfloat16(v);
    }
    __syncthreads();
    #pragma unroll
    for (int it = 0; it < 16; it++) {
        int idx = t + it * 256;
        int u = idx >> 6, i = idx & 63;
        float v = Ls[i * 65 + u];
        __hip_bfloat16 h = __float2bfloat16(v);
        size_t o = (size_t)(b * 64 + u) * N_NODES + n0 + i;
        xh[o] = h;
        xl[o] = __float2bfloat16(v - __bfloat162float(h));
    }
}

// ---------------- GEMM1 (coarse projection, split-K): part[z] = x0sT_ext @ afc^T ----------------
// Out[j][c], M=4224, N=256, K=2048; 3-term split. OCCUPANCY-FIRST variant:
// 64x128 (m x c) tile, 4 waves as 2x2, each wave 32m x 64c -> acc[2][4] = 32 AGPR only
// (~100 regs total -> ~5 waves/SIMD budget). Grid 1056 = 4.1 blocks/CU (vs 2.06 before),
// 3% tail. No LDS/barriers; direct global fragments; compiler JIT-schedules, cross-wave
// TLP hides the load latency. XCD pairing: c-pair distance 528 (%8==0), m-neighbors 8.
__global__ __launch_bounds__(256) void gemm1_reg(
    const __hip_bfloat16* __restrict__ Ah, const __hip_bfloat16* __restrict__ Al,  // x0sT h/l [4224][2048]
    const __hip_bfloat16* __restrict__ Bh, const __hip_bfloat16* __restrict__ Bl,  // afc h/l [256][2048]
    float* __restrict__ part)
{
    const int K = N_NODES;
    int tid  = threadIdx.x;
    int wave = tid >> 6, lane = tid & 63;
    int quad = lane >> 4, lr = lane & 15;
    int wr = wave >> 1, wc = wave & 1;

    int wgid = blockIdx.x;
    int cblk = wgid / 528;            // 0..1
    int rest = wgid % 528;
    int mblk = rest >> 3;             // 0..65
    int zblk = rest & 7;              // 0..7
    int mBase = mblk * 64;
    int nBase = cblk * 128;
    int k0base = zblk * (K / ZSPLIT); // 256-wide K slice

    const short* Ah_ = (const short*)Ah;
    const short* Al_ = (const short*)Al;
    const short* Bh_ = (const short*)Bh;
    const short* Bl_ = (const short*)Bl;

    size_t aoff[2], boff[4];
    #pragma unroll
    for (int i = 0; i < 2; i++)
        aoff[i] = (size_t)(mBase + wr * 32 + i * 16 + lr) * K + k0base + quad * 8;
    #pragma unroll
    for (int j = 0; j < 4; j++)
        boff[j] = (size_t)(nBase + wc * 64 + j * 16 + lr) * K + k0base + quad * 8;

    f32x4 acc[2][4];
    #pragma unroll
    for (int i = 0; i < 2; i++)
        #pragma unroll
        for (int j = 0; j < 4; j++) { f32x4 z = {0.f,0.f,0.f,0.f}; acc[i][j] = z; }

    #pragma unroll
    for (int ks = 0; ks < 8; ks++) {        // 8 MFMA k-steps of 32 over K=256
        int ko = ks * 32;
        s16x8 ah[2], al[2], bh[4], bl[4];
        #pragma unroll
        for (int i = 0; i < 2; i++) {
            ah[i] = *(const s16x8*)(Ah_ + aoff[i] + ko);
            al[i] = *(const s16x8*)(Al_ + aoff[i] + ko);
        }
        #pragma unroll
        for (int j = 0; j < 4; j++) {
            bh[j] = *(const s16x8*)(Bh_ + boff[j] + ko);
            bl[j] = *(const s16x8*)(Bl_ + boff[j] + ko);
        }
        #pragma unroll
        for (int i = 0; i < 2; i++)
            #pragma unroll
            for (int j = 0; j < 4; j++) {
                acc[i][j] = __builtin_amdgcn_mfma_f32_16x16x32_bf16(ah[i], bh[j], acc[i][j], 0, 0, 0);
                acc[i][j] = __builtin_amdgcn_mfma_f32_16x16x32_bf16(ah[i], bl[j], acc[i][j], 0, 0, 0);
                acc[i][j] = __builtin_amdgcn_mfma_f32_16x16x32_bf16(al[i], bh[j], acc[i][j], 0, 0, 0);
            }
    }

    float* dst = part + (size_t)zblk * JSX * C_NODES;
    #pragma unroll
    for (int i = 0; i < 2; i++)
        #pragma unroll
        for (int j = 0; j < 4; j++)
            #pragma unroll
            for (int r = 0; r < 4; r++) {
                int row = mBase + wr * 32 + i * 16 + quad * 4 + r;
                int col = nBase + wc * 64 + j * 16 + lr;
                dst[(size_t)row * C_NODES + col] = acc[i][j][r];
            }
}

// reduce ZSPLIT split-K partials -> hi/lo bf16 pair
__global__ __launch_bounds__(256) void reduce_split(const float* __restrict__ part,
                                                    __hip_bfloat16* __restrict__ oh,
                                                    __hip_bfloat16* __restrict__ ol, int n)
{
    int stride = gridDim.x * 256;
    const size_t slice = (size_t)JSX * C_NODES;
    for (int i = blockIdx.x * 256 + threadIdx.x; i < n; i += stride) {
        float v = 0.f;
        #pragma unroll
        for (int s = 0; s < ZSPLIT; s++) v += part[s * slice + i];
        __hip_bfloat16 h = __float2bfloat16(v);
        oh[i] = h;
        ol[i] = __float2bfloat16(v - __bfloat162float(h));
    }
}

// ---------------- coarse GEMM: x1 = sigmoid(afct@x0fc) (K=256, 3-term split) ----------------
// M=2048(n) x N=4224(j), 128x128 tiles, grid (33,16).
// Output in BATCH-BLOCKED layout: x1B[j>>6][n][j&63]  (66 blocks of [2048][64]).
__global__ __launch_bounds__(256, 2) void gemm_coarse(
    const __hip_bfloat16* __restrict__ Ah, const __hip_bfloat16* __restrict__ Al,  // afct h/l [2048][256]
    const __hip_bfloat16* __restrict__ Bh, const __hip_bfloat16* __restrict__ Bl,  // x0fcT h/l [4224][256]
    __hip_bfloat16* __restrict__ OutH, __hip_bfloat16* __restrict__ OutL)
{
    __shared__ __align__(16) __hip_bfloat16 S1[8192];
    __shared__ __align__(16) __hip_bfloat16 S2[8192];
    __shared__ __align__(16) __hip_bfloat16 S3[8192];
    __shared__ __align__(16) __hip_bfloat16 S4[8192];   // 64 KB

    int tid  = threadIdx.x;
    int wave = tid >> 6, lane = tid & 63;
    int quad = lane >> 4, lr = lane & 15;
    int wr = wave >> 1, wc = wave & 1;
    int mBase = blockIdx.y * 128, nBase = blockIdx.x * 128;

    int cellkb[4], cellmm[4];
    #pragma unroll
    for (int ch = 0; ch < 4; ch++) {
        int cell = (wave * 4 + ch) * 64 + lane;
        cellkb[ch] = cell >> 7;
        cellmm[ch] = cell & 127;
    }

    f32x4 acc[4][4];
    #pragma unroll
    for (int i = 0; i < 4; i++)
        #pragma unroll
        for (int j = 0; j < 4; j++) { f32x4 z = {0.f,0.f,0.f,0.f}; acc[i][j] = z; }

    for (int k0 = 0; k0 < C_NODES; k0 += 64) {
        #pragma unroll
        for (int ch = 0; ch < 4; ch++) {
            size_t offA = (size_t)(mBase + cellmm[ch]) * C_NODES + k0 + cellkb[ch] * 8;
            size_t offB = (size_t)(nBase + cellmm[ch]) * C_NODES + k0 + cellkb[ch] * 8;
            int lo = (wave * 4 + ch) * 512;
            gload_lds16(Ah + offA, S1 + lo);
            gload_lds16(Al + offA, S2 + lo);
            gload_lds16(Bh + offB, S3 + lo);
            gload_lds16(Bl + offB, S4 + lo);
        }
        __syncthreads();
        const s16x8* AhV = (const s16x8*)S1;
        const s16x8* AlV = (const s16x8*)S2;
        const s16x8* BhV = (const s16x8*)S3;
        const s16x8* BlV = (const s16x8*)S4;
        #pragma unroll
        for (int ks = 0; ks < 2; ks++) {
            int kb = ks * 4 + quad;
            s16x8 ah[4], al[4], bh[4], bl[4];
            #pragma unroll
            for (int i = 0; i < 4; i++) {
                int idx = kb * 128 + wr * 64 + i * 16 + lr;
                ah[i] = AhV[idx]; al[i] = AlV[idx];
            }
            #pragma unroll
            for (int j = 0; j < 4; j++) {
                int idx = kb * 128 + wc * 64 + j * 16 + lr;
                bh[j] = BhV[idx]; bl[j] = BlV[idx];
            }
            #pragma unroll
            for (int i = 0; i < 4; i++)
                #pragma unroll
                for (int j = 0; j < 4; j++) {
                    acc[i][j] = __builtin_amdgcn_mfma_f32_16x16x32_bf16(ah[i], bh[j], acc[i][j], 0, 0, 0);
                    acc[i][j] = __builtin_amdgcn_mfma_f32_16x16x32_bf16(ah[i], bl[j], acc[i][j], 0, 0, 0);
                    acc[i][j] = __builtin_amdgcn_mfma_f32_16x16x32_bf16(al[i], bh[j], acc[i][j], 0, 0, 0);
                }
        }
        __syncthreads();
    }

    #pragma unroll
    for (int i = 0; i < 4; i++)
        #pragma unroll
        for (int j = 0; j < 4; j++)
            #pragma unroll
            for (int r = 0; r < 4; r++) {
                int row = mBase + wr * 64 + i * 16 + quad * 4 + r;
                int col = nBase + wc * 64 + j * 16 + lr;
                float v = sigmoidf_(acc[i][j][r]);
                size_t idx = (size_t)(col >> 6) * NU + (size_t)row * 64 + (col & 63);
                __hip_bfloat16 h = __float2bfloat16(v);
                OutH[idx] = h;
                OutL[idx] = __float2bfloat16(v - __bfloat162float(h));
            }
}

// ---------------- SpMM: x1B += adj @ X (f32 adj vals, bf16 X rows) ----------------
// 1D XCD-pinned grid: wgid<4096: jt = wgid&7 (all blocks of a j-tile on ONE XCD ->
// its 2MB X column slice stays L2-resident), nb = wgid>>3. wgid>=4096: jt=8 (input cols).
// Block = 4 waves, wave-per-node. CSR metadata staged in LDS (broadcast reads, addresses
// available early); gather loop unrolled 8 for deep VMEM pipelining.
__global__ __launch_bounds__(256) void spmm_add(
    const __hip_bfloat16* __restrict__ X,
    const unsigned short* __restrict__ cols,
    const float* __restrict__ vals,
    const int* __restrict__ nnz,
    __hip_bfloat16* __restrict__ OutH,
    __hip_bfloat16* __restrict__ OutL)
{
    __shared__ unsigned short colS[4 * CAP];
    __shared__ float          valS[4 * CAP];
    __shared__ int            cntS[4];

    int tid  = threadIdx.x;
    int wave = tid >> 6, lane = tid & 63;
    int wgid = blockIdx.x;
    int jt, nb;
    if (wgid < 4096) { jt = wgid & 7; nb = wgid >> 3; }
    else             { jt = 8;        nb = wgid - 4096; }
    int nBase = nb * 4;

    // stage CSR metadata for the block's 4 nodes (contiguous in cols/vals)
    if (tid < 4) cntS[tid] = nnz[nBase + tid];
    {
        const unsigned short* cpg = cols + (size_t)nBase * CAP;
        const float*          vpg = vals + (size_t)nBase * CAP;
        #pragma unroll
        for (int it = 0; it < 3; it++) {
            int idx = tid + it * 256;
            colS[idx] = cpg[idx];
            valS[idx] = vpg[idx];
        }
    }
    __syncthreads();

    int n   = nBase + wave;
    int cnt = cntS[wave];
    const unsigned short* cp = colS + wave * CAP;
    const float*          vp = valS + wave * CAP;
    const short* Xs = (const short*)X;

    if (jt < 8) {
        int j0 = jt * 512 + lane * 8;
        float acc[8];
        #pragma unroll
        for (int e = 0; e < 8; e++) acc[e] = 0.f;
        int i = 0;
        for (; i + 8 <= cnt; i += 8) {
            int   c[8]; float a[8];
            #pragma unroll
            for (int q = 0; q < 8; q++) { c[q] = cp[i + q]; a[q] = vp[i + q]; }
            s16x8 xv[8];
            #pragma unroll
            for (int q = 0; q < 8; q++)
                xv[q] = *(const s16x8*)(Xs + (size_t)c[q] * XSTR + j0);
            #pragma unroll
            for (int q = 0; q < 8; q++)
                #pragma unroll
                for (int e = 0; e < 8; e++) acc[e] += a[q] * bfs2f(xv[q][e]);
        }
        for (; i < cnt; i++) {
            int c = cp[i]; float a = vp[i];
            s16x8 xv = *(const s16x8*)(Xs + (size_t)c * XSTR + j0);
            #pragma unroll
            for (int e = 0; e < 8; e++) acc[e] += a * bfs2f(xv[e]);
        }
        // blocked: j = jt*512 + lane*8 -> block = jt*8 + (lane>>3), u = (lane&7)*8
        size_t o = (size_t)(jt * 8 + (lane >> 3)) * NU + (size_t)n * 64 + (lane & 7) * 8;
        s16x8 h = *(const s16x8*)((const short*)OutH + o);
        s16x8 l = *(const s16x8*)((const short*)OutL + o);
        s16x8 nh, nl;
        #pragma unroll
        for (int e = 0; e < 8; e++) {
            float v = bfs2f(h[e]) + bfs2f(l[e]) + acc[e];
            short hh = f2bfs(v);
            nh[e] = hh;
            nl[e] = f2bfs(v - bfs2f(hh));
        }
        *(s16x8*)((short*)OutH + o) = nh;
        *(s16x8*)((short*)OutL + o) = nl;
    } else {
        float acc = 0.f;
        int i = 0;
        for (; i + 8 <= cnt; i += 8) {
            int   c[8]; float a[8];
            #pragma unroll
            for (int q = 0; q < 8; q++) { c[q] = cp[i + q]; a[q] = vp[i + q]; }
            short xv[8];
            #pragma unroll
            for (int q = 0; q < 8; q++) xv[q] = Xs[(size_t)c[q] * XSTR + 4096 + lane];
            #pragma unroll
            for (int q = 0; q < 8; q++) acc += a[q] * bfs2f(xv[q]);
        }
        for (; i < cnt; i++) {
            int c = cp[i]; float a = vp[i];
            acc += a * bfs2f(Xs[(size_t)c * XSTR + 4096 + lane]);
        }
        size_t o = (size_t)64 * NU + (size_t)n * 64 + lane;   // block 64, u = lane(=b)
        float v = bfs2f(((const short*)OutH)[o]) + bfs2f(((const short*)OutL)[o]) + acc;
        short hh = f2bfs(v);
        ((short*)OutH)[o] = hh;
        ((short*)OutL)[o] = f2bfs(v - bfs2f(hh));
    }
}

// ---------------- head1 (split MFMA): gates = x1s @ w0T + w0_row0*xin + b0 ----------------
// x1B blocked input: A-fragments loaded DIRECTLY from global (coalesced 64B segments).
// W fragments direct from global (L1-resident). LDS only for the x0sT transpose (XOR-swizzled).
// launch_bounds (256,3): VGPR cap 170 so the per-i state preloads batch into one load cluster.
__global__ __launch_bounds__(256, 3) void head1_mfma(
    const __hip_bfloat16* __restrict__ x1h, const __hip_bfloat16* __restrict__ x1l,
    const __hip_bfloat16* __restrict__ Wh, const __hip_bfloat16* __restrict__ Wl,
    const float* __restrict__ w0, const float* __restrict__ b0,
    const float* __restrict__ state,
    __hip_bfloat16* __restrict__ xh, __hip_bfloat16* __restrict__ xl,
    __hip_bfloat16* __restrict__ u_buf,
    __hip_bfloat16* __restrict__ Xout)
{
    __shared__ __align__(16) short trH[8192];   // [64 o][128 n], n XOR-swizzled by (o&15)<<3
    __shared__ __align__(16) short trL[8192];
    __shared__ float xinS[128];

    int n0 = blockIdx.x * 128;
    int b  = blockIdx.y;
    int tid = threadIdx.x;
    int wave = tid >> 6, lane = tid & 63;
    int quad = lane >> 4, lr = lane & 15;
    int wr = wave >> 1, wc = wave & 1;

    if (tid < 128) {
        size_t o = (size_t)64 * NU + (size_t)(n0 + tid) * 64 + b;
        xinS[tid] = __bfloat162float(x1h[o]) + __bfloat162float(x1l[o]);
    }

    f32x4 acc[4][4];
    #pragma unroll
    for (int i = 0; i < 4; i++)
        #pragma unroll
        for (int j = 0; j < 4; j++) { f32x4 z = {0.f,0.f,0.f,0.f}; acc[i][j] = z; }

    const short* Xh = (const short*)x1h + (size_t)b * NU;
    const short* Xl = (const short*)x1l + (size_t)b * NU;
    const short* Wh_ = (const short*)Wh;
    const short* Wl_ = (const short*)Wl;

    #pragma unroll
    for (int ks = 0; ks < 2; ks++) {
        s16x8 ah[4], al[4];
        #pragma unroll
        for (int i = 0; i < 4; i++) {
            size_t off = (size_t)(n0 + wr * 64 + i * 16 + lr) * 64 + ks * 32 + quad * 8;
            ah[i] = *(const s16x8*)(Xh + off);
            al[i] = *(const s16x8*)(Xl + off);
        }
        #pragma unroll
        for (int j = 0; j < 4; j++) {
            size_t wo = ((size_t)(ks * 4 + quad) * 128 + wc * 64 + j * 16 + lr) * 8;
            s16x8 bh = *(const s16x8*)(Wh_ + wo);
            s16x8 bl = *(const s16x8*)(Wl_ + wo);
            #pragma unroll
            for (int i = 0; i < 4; i++) {
                acc[i][j] = __builtin_amdgcn_mfma_f32_16x16x32_bf16(ah[i], bh, acc[i][j], 0, 0, 0);
                acc[i][j] = __builtin_amdgcn_mfma_f32_16x16x32_bf16(ah[i], bl, acc[i][j], 0, 0, 0);
                acc[i][j] = __builtin_amdgcn_mfma_f32_16x16x32_bf16(al[i], bh, acc[i][j], 0, 0, 0);
            }
        }
    }
    __syncthreads();   // xinS ready

    if (wc == 0) {
        #pragma unroll
        for (int i = 0; i < 4; i++) {
            // batched preload: 16 independent state loads in flight, then compute
            float sv[4][4];
            #pragma unroll
            for (int j = 0; j < 4; j++)
                #pragma unroll
                for (int r = 0; r < 4; r++)
                    sv[j][r] = state[(size_t)b * NU
                                     + (size_t)(n0 + wr * 64 + i * 16 + quad * 4 + r) * 64
                                     + j * 16 + lr];
            #pragma unroll
            for (int j = 0; j < 4; j++)
                #pragma unroll
                for (int r = 0; r < 4; r++) {
                    int n_loc = wr * 64 + i * 16 + quad * 4 + r;
                    int o = j * 16 + lr;
                    float g = acc[i][j][r] + w0[o] * xinS[n_loc] + b0[o];
                    float sg = sigmoidf_(g);
                    float rs = sg * sv[j][r];
                    short h = f2bfs(rs);
                    int sw = n_loc ^ ((o & 15) << 3);
                    trH[o * 128 + sw] = h;
                    trL[o * 128 + sw] = f2bfs(rs - bfs2f(h));
                    ((short*)Xout)[(size_t)(n0 + n_loc) * XSTR + b * 64 + o] = h;
                }
        }
    } else {
        #pragma unroll
        for (int i = 0; i < 4; i++)
            #pragma unroll
            for (int j = 0; j < 4; j++)
                #pragma unroll
                for (int r = 0; r < 4; r++) {
                    int n_loc = wr * 64 + i * 16 + quad * 4 + r;
                    int o = 64 + j * 16 + lr;
                    float g = acc[i][j][r] + w0[o] * xinS[n_loc] + b0[o];
                    float sg = sigmoidf_(g);
                    u_buf[(size_t)b * NU + (size_t)(n0 + n_loc) * 64 + (o - 64)] = __float2bfloat16(sg);
                }
    }
    __syncthreads();

    {
        int row = tid >> 2, seg = tid & 3;
        int xorv = (row & 15) << 3;
        short* dh = (short*)xh + (size_t)(b * 64 + row) * N_NODES + n0 + seg * 32;
        short* dl = (short*)xl + (size_t)(b * 64 + row) * N_NODES + n0 + seg * 32;
        #pragma unroll
        for (int q = 0; q < 4; q++) {
            int src = row * 128 + ((seg * 32 + q * 8) ^ xorv);
            *(uint4*)(dh + q * 8) = *(const uint4*)(trH + src);
            *(uint4*)(dl + q * 8) = *(const uint4*)(trL + src);
        }
    }
}

// ---------------- head2 (split MFMA): out = u*s + (1-u)*tanh(x1s@w1T + w1_row0*xin + b1) ----------------
// A-fragments + W fragments direct from global; no LDS except xinS.
// launch_bounds (256,3): room to batch ALL 32 state + 32 u_buf loads before the tanh loop.
__global__ __launch_bounds__(256, 3) void head2_mfma(
    const __hip_bfloat16* __restrict__ x1h, const __hip_bfloat16* __restrict__ x1l,
    const __hip_bfloat16* __restrict__ Wh, const __hip_bfloat16* __restrict__ Wl,
    const float* __restrict__ w1, const float* __restrict__ b1,
    const float* __restrict__ state, const __hip_bfloat16* __restrict__ u_buf,
    float* __restrict__ out)
{
    __shared__ float xinS[128];

    int n0 = blockIdx.x * 128;
    int b  = blockIdx.y;
    int tid = threadIdx.x;
    int wave = tid >> 6, lane = tid & 63;
    int quad = lane >> 4, lr = lane & 15;

    if (tid < 128) {
        size_t o = (size_t)64 * NU + (size_t)(n0 + tid) * 64 + b;
        xinS[tid] = __bfloat162float(x1h[o]) + __bfloat162float(x1l[o]);
    }

    f32x4 acc[2][4];
    #pragma unroll
    for (int i = 0; i < 2; i++)
        #pragma unroll
        for (int j = 0; j < 4; j++) { f32x4 z = {0.f,0.f,0.f,0.f}; acc[i][j] = z; }

    const short* Xh = (const short*)x1h + (size_t)b * NU;
    const short* Xl = (const short*)x1l + (size_t)b * NU;
    const short* Wh_ = (const short*)Wh;
    const short* Wl_ = (const short*)Wl;

    #pragma unroll
    for (int ks = 0; ks < 2; ks++) {
        s16x8 ah[2], al[2];
        #pragma unroll
        for (int i = 0; i < 2; i++) {
            size_t off = (size_t)(n0 + wave * 32 + i * 16 + lr) * 64 + ks * 32 + quad * 8;
            ah[i] = *(const s16x8*)(Xh + off);
            al[i] = *(const s16x8*)(Xl + off);
        }
        #pragma unroll
        for (int j = 0; j < 4; j++) {
            size_t wo = ((size_t)(ks * 4 + quad) * 64 + j * 16 + lr) * 8;
            s16x8 bh = *(const s16x8*)(Wh_ + wo);
            s16x8 bl = *(const s16x8*)(Wl_ + wo);
            #pragma unroll
            for (int i = 0; i < 2; i++) {
                acc[i][j] = __builtin_amdgcn_mfma_f32_16x16x32_bf16(ah[i], bh, acc[i][j], 0, 0, 0);
                acc[i][j] = __builtin_amdgcn_mfma_f32_16x16x32_bf16(ah[i], bl, acc[i][j], 0, 0, 0);
                acc[i][j] = __builtin_amdgcn_mfma_f32_16x16x32_bf16(al[i], bh, acc[i][j], 0, 0, 0);
            }
        }
    }
    __syncthreads();   // xinS ready

    // batched preload of state + u (64 independent loads in flight)
    float sv[2][4][4];
    float uv[2][4][4];
    #pragma unroll
    for (int i = 0; i < 2; i++)
        #pragma unroll
        for (int j = 0; j < 4; j++)
            #pragma unroll
            for (int r = 0; r < 4; r++) {
                size_t sidx = (size_t)b * NU
                            + (size_t)(n0 + wave * 32 + i * 16 + quad * 4 + r) * 64
                            + j * 16 + lr;
                sv[i][j][r] = state[sidx];
                uv[i][j][r] = __bfloat162float(u_buf[sidx]);
            }

    #pragma unroll
    for (int i = 0; i < 2; i++)
        #pragma unroll
        for (int j = 0; j < 4; j++)
            #pragma unroll
            for (int r = 0; r < 4; r++) {
                int n_loc = wave * 32 + i * 16 + quad * 4 + r;
                int o = j * 16 + lr;
                float g = acc[i][j][r] + w1[o] * xinS[n_loc] + b1[o];
                float c = tanhf(g);
                size_t sidx = (size_t)b * NU + (size_t)(n0 + n_loc) * 64 + o;
                float ug = uv[i][j][r];
                float svv = sv[i][j][r];
                out[sidx] = ug * svv + (1.0f - ug) * c;
            }
}

extern "C" void kernel_launch(void* const* d_in, const int* in_sizes, int n_in,
                              void* d_out, int out_size, void* d_ws, size_t ws_size,
                              hipStream_t stream)
{
    const float* inputs = (const float*)d_in[0];
    const float* state  = (const float*)d_in[1];
    const float* adj    = (const float*)d_in[2];
    // d_in[3] = adj1 : unused (discarded outfc path)
    const float* afc    = (const float*)d_in[4];   // [C][N]
    const float* afct   = (const float*)d_in[5];   // [N][C]
    const float* w0     = (const float*)d_in[6];
    const float* b0     = (const float*)d_in[7];
    const float* w1     = (const float*)d_in[8];
    const float* b1     = (const float*)d_in[9];
    // d_in[10..13]: unused

    float* out = (float*)d_out;

    char* p = (char*)d_ws;
    __hip_bfloat16* afc_h    = (__hip_bfloat16*)p; p += (size_t)C_NODES * N_NODES * 2;
    __hip_bfloat16* afc_l    = (__hip_bfloat16*)p; p += (size_t)C_NODES * N_NODES * 2;
    __hip_bfloat16* afct_h   = (__hip_bfloat16*)p; p += (size_t)N_NODES * C_NODES * 2;
    __hip_bfloat16* afct_l   = (__hip_bfloat16*)p; p += (size_t)N_NODES * C_NODES * 2;
    __hip_bfloat16* w0T_h    = (__hip_bfloat16*)p; p += 8192 * 2;
    __hip_bfloat16* w0T_l    = (__hip_bfloat16*)p; p += 8192 * 2;
    __hip_bfloat16* w1T_h    = (__hip_bfloat16*)p; p += 4096 * 2;
    __hip_bfloat16* w1T_l    = (__hip_bfloat16*)p; p += 4096 * 2;
    __hip_bfloat16* x0sT_h   = (__hip_bfloat16*)p; p += (size_t)JSX * N_NODES * 2;       // 17.3 MB
    __hip_bfloat16* x0sT_l   = (__hip_bfloat16*)p; p += (size_t)JSX * N_NODES * 2;
    __hip_bfloat16* x0fcT_h  = (__hip_bfloat16*)p; p += (size_t)JSX * C_NODES * 2;       // 2.16 MB
    __hip_bfloat16* x0fcT_l  = (__hip_bfloat16*)p; p += (size_t)JSX * C_NODES * 2;
    // part (ZSPLIT x JSX x 256 f32 = 34.6 MB) ALIASES x1B_h/x1B_l (34.6 MB):
    // part is live only gemm1->reduce; x1B is fully rewritten by gemm_coarse afterwards.
    float*          part     = (float*)p;
    __hip_bfloat16* x1B_h    = (__hip_bfloat16*)p; p += (size_t)66 * NU * 2;             // 17.3 MB (batch-blocked)
    __hip_bfloat16* x1B_l    = (__hip_bfloat16*)p; p += (size_t)66 * NU * 2;
    __hip_bfloat16* u_buf    = (__hip_bfloat16*)p; p += (size_t)BATCH * NU * 2;          // 16.78 MB
    __hip_bfloat16* X        = (__hip_bfloat16*)p; p += (size_t)N_NODES * XSTR * 2;      // 17.04 MB
    unsigned short* csr_cols = (unsigned short*)p; p += (size_t)N_NODES * CAP * 2;       // 0.79 MB
    float*          csr_vals = (float*)p;          p += (size_t)N_NODES * CAP * 4;       // 1.57 MB
    int*            csr_nnz  = (int*)p;            p += (size_t)N_NODES * 4;
    // total ~114 MB

    dim3 blk(256);

    // ---- once: converts + CSR + extended-row setup ----
    cvt_split<<<256,  blk, 0, stream>>>(afc,  afc_h,  afc_l,  C_NODES * N_NODES);
    cvt_split<<<256,  blk, 0, stream>>>(afct, afct_h, afct_l, N_NODES * C_NODES);
    cvt_w    <<<32,   blk, 0, stream>>>(w0, w1, w0T_h, w0T_l, w1T_h, w1T_l);
    setup_ext<<<128,  blk, 0, stream>>>(inputs, x0sT_h, x0sT_l, x0fcT_h, x0fcT_l, X);
    build_csr<<<512,  blk, 0, stream>>>(adj, csr_cols, csr_vals, csr_nnz);

    // ---- pass 1 ----
    build_x0sT<<<dim3(32, 64), blk, 0, stream>>>(state, x0sT_h, x0sT_l, X);
    gemm1_reg<<<dim3(1056), blk, 0, stream>>>(x0sT_h, x0sT_l, afc_h, afc_l, part);
    reduce_split<<<1024, blk, 0, stream>>>(part, x0fcT_h, x0fcT_l, NX * C_NODES);
    gemm_coarse<<<dim3(33, 16), blk, 0, stream>>>(afct_h, afct_l, x0fcT_h, x0fcT_l, x1B_h, x1B_l);
    spmm_add<<<dim3(4608), blk, 0, stream>>>(X, csr_cols, csr_vals, csr_nnz, x1B_h, x1B_l);
    head1_mfma<<<dim3(16, 64), blk, 0, stream>>>(x1B_h, x1B_l, w0T_h, w0T_l, w0, b0,
                                                 state, x0sT_h, x0sT_l, u_buf, X);

    // ---- pass 2 (x0sT/X state rows now hold r*state; input rows unchanged) ----
    gemm1_reg<<<dim3(1056), blk, 0, stream>>>(x0sT_h, x0sT_l, afc_h, afc_l, part);
    reduce_split<<<1024, blk, 0, stream>>>(part, x0fcT_h, x0fcT_l, NX * C_NODES);
    gemm_coarse<<<dim3(33, 16), blk, 0, stream>>>(afct_h, afct_l, x0fcT_h, x0fcT_l, x1B_h, x1B_l);
    spmm_add<<<dim3(4608), blk, 0, stream>>>(X, csr_cols, csr_vals, csr_nnz, x1B_h, x1B_l);
    head2_mfma<<<dim3(16, 64), blk, 0, stream>>>(x1B_h, x1B_l, w1T_h, w1T_l, w1, b1,
                                                 state, u_buf, out);
}

// Round 10
// 481.465 us; speedup vs baseline: 1.0173x; 1.0173x over previous
//
#include <hip/hip_runtime.h>
#include <hip/hip_bf16.h>
#include <math.h>

#define N_NODES 2048
#define C_NODES 256
#define BATCH   64
#define UNITS   64
#define JS      4096                // state-part columns: j = b*64+u
#define NX      4160                // + 64 input-channel columns
#define JSX     4224                // padded to 33 x 128 tiles (66 x 64-blocks)
#define NU      131072              // N_NODES * UNITS
#define XSTR    4160                // X row stride (state cols + input cols)
#define CAP     192                 // max nnz per adj row (mean ~33)
#define ZSPLIT  8                   // gemm1 split-K factor

typedef short  s16x8 __attribute__((ext_vector_type(8)));   // 8 bf16 in 4 VGPRs
typedef float  f32x4 __attribute__((ext_vector_type(4)));

__device__ __forceinline__ float sigmoidf_(float x) { return 1.0f / (1.0f + __expf(-x)); }

__device__ __forceinline__ float bfs2f(short s) {
    union { float f; unsigned u; } w; w.u = ((unsigned)(unsigned short)s) << 16; return w.f;
}
__device__ __forceinline__ short f2bfs(float f) {
    __hip_bfloat16 h = __float2bfloat16(f);
    short s; __builtin_memcpy(&s, &h, 2); return s;
}

__device__ __forceinline__ void gload_lds16(const void* g, void* l) {
    __builtin_amdgcn_global_load_lds(
        (const __attribute__((address_space(1))) void*)g,
        (__attribute__((address_space(3))) void*)l, 16, 0, 0);
}

// ---------------- converts ----------------
__global__ __launch_bounds__(256) void cvt_split(const float* __restrict__ s,
                                                 __hip_bfloat16* __restrict__ dh,
                                                 __hip_bfloat16* __restrict__ dl, int n)
{
    int stride = gridDim.x * 256;
    for (int i = blockIdx.x * 256 + threadIdx.x; i < n; i += stride) {
        float v = s[i];
        __hip_bfloat16 h = __float2bfloat16(v);
        dh[i] = h;
        dl[i] = __float2bfloat16(v - __bfloat162float(h));
    }
}

// w0[65][128], w1[65][64] -> blocked transposed bf16 h/l: cell (c*O+o), elem jj = w[(1+c*8+jj)*O + o]
__global__ __launch_bounds__(256) void cvt_w(const float* __restrict__ w0,
                                             const float* __restrict__ w1,
                                             __hip_bfloat16* __restrict__ w0h, __hip_bfloat16* __restrict__ w0l,
                                             __hip_bfloat16* __restrict__ w1h, __hip_bfloat16* __restrict__ w1l)
{
    int stride = gridDim.x * 256;
    for (int e = blockIdx.x * 256 + threadIdx.x; e < 8192 + 4096; e += stride) {
        if (e < 8192) {  // w0T: O=128
            int jj = e & 7, cell = e >> 3;
            int o = cell & 127, c = cell >> 7;
            float v = w0[(size_t)(1 + c * 8 + jj) * 128 + o];
            __hip_bfloat16 h = __float2bfloat16(v);
            w0h[e] = h; w0l[e] = __float2bfloat16(v - __bfloat162float(h));
        } else {         // w1T: O=64
            int e2 = e - 8192;
            int jj = e2 & 7, cell = e2 >> 3;
            int o = cell & 63, c = cell >> 6;
            float v = w1[(size_t)(1 + c * 8 + jj) * 64 + o];
            __hip_bfloat16 h = __float2bfloat16(v);
            w1h[e2] = h; w1l[e2] = __float2bfloat16(v - __bfloat162float(h));
        }
    }
}

// once: x0sT rows 4096..4159 = inputs (hi/lo); X input cols; zero rows 4160..4223 of x0sT/x0fcT
__global__ __launch_bounds__(256) void setup_ext(
    const float* __restrict__ inputs,
    __hip_bfloat16* __restrict__ xh, __hip_bfloat16* __restrict__ xl,
    __hip_bfloat16* __restrict__ fh, __hip_bfloat16* __restrict__ fl,
    __hip_bfloat16* __restrict__ X)
{
    int blk = blockIdx.x;
    if (blk < 64) {
        int b = blk;
        for (int n = threadIdx.x; n < N_NODES; n += 256) {
            float v = inputs[(size_t)b * N_NODES + n];
            __hip_bfloat16 h = __float2bfloat16(v);
            size_t o = (size_t)(JS + b) * N_NODES + n;
            xh[o] = h;
            xl[o] = __float2bfloat16(v - __bfloat162float(h));
            X[(size_t)n * XSTR + 4096 + b] = h;   // input cols of X (once; never rewritten)
        }
    } else {
        int r = NX + (blk - 64);   // 4160..4223
        __hip_bfloat16 z = __float2bfloat16(0.0f);
        for (int n = threadIdx.x; n < N_NODES; n += 256) {
            size_t o = (size_t)r * N_NODES + n;
            xh[o] = z; xl[o] = z;
        }
        for (int c = threadIdx.x; c < C_NODES; c += 256) {
            size_t o = (size_t)r * C_NODES + c;
            fh[o] = z; fl[o] = z;
        }
    }
}

// ---------------- adj -> CSR (once). One wave per row, ballot compaction ----------------
__global__ __launch_bounds__(256) void build_csr(
    const float* __restrict__ adj,
    unsigned short* __restrict__ cols,
    float* __restrict__ vals,
    int* __restrict__ nnz)
{
    int row  = blockIdx.x * 4 + (threadIdx.x >> 6);
    int lane = threadIdx.x & 63;
    const float* a = adj + (size_t)row * N_NODES;
    int base = 0;
    for (int k0 = 0; k0 < N_NODES; k0 += 64) {
        float v = a[k0 + lane];
        unsigned long long m = __ballot(v != 0.0f);
        if (v != 0.0f) {
            int pos = base + __popcll(m & ((1ull << lane) - 1));
            if (pos < CAP) {
                cols[(size_t)row * CAP + pos] = (unsigned short)(k0 + lane);
                vals[(size_t)row * CAP + pos] = v;
            }
        }
        base += __popcll(m);
    }
    if (lane == 0) nnz[row] = base < CAP ? base : CAP;
}

// pass-1 x0sT build: state[b][n*64+u] -> x0sT_h/l[(b*64+u)][n]; also X[n][b*64+u] = bf16(state)
__global__ __launch_bounds__(256) void build_x0sT(const float* __restrict__ st,
                                                  __hip_bfloat16* __restrict__ xh,
                                                  __hip_bfloat16* __restrict__ xl,
                                                  __hip_bfloat16* __restrict__ X)
{
    __shared__ float Ls[64 * 65];
    int n0 = blockIdx.x * 64;
    int b  = blockIdx.y;
    int t  = threadIdx.x;
    #pragma unroll
    for (int it = 0; it < 16; it++) {
        int idx = t + it * 256;
        int i = idx >> 6, u = idx & 63;
        float v = st[(size_t)b * NU + (size_t)(n0 + i) * 64 + u];
        Ls[i * 65 + u] = v;
        X[(size_t)(n0 + i) * XSTR + b * 64 + u] = __float2bfloat16(v);
    }
    __syncthreads();
    #pragma unroll
    for (int it = 0; it < 16; it++) {
        int idx = t + it * 256;
        int u = idx >> 6, i = idx & 63;
        float v = Ls[i * 65 + u];
        __hip_bfloat16 h = __float2bfloat16(v);
        size_t o = (size_t)(b * 64 + u) * N_NODES + n0 + i;
        xh[o] = h;
        xl[o] = __float2bfloat16(v - __bfloat162float(h));
    }
}

// ---------------- GEMM1 (coarse projection, split-K): part[z] = x0sT_ext @ afc^T ----------------
// Out[j][c], M=4224, N=256, K=2048; 128x128 tiles; 3-term split. grid (2, 33, ZSPLIT).
// Per K-iteration: [hoisted B-frag global loads (issued first => waited first)]
// [async A-stage of NEXT slice into dbuf (drains at end barrier)] [LDS reads + 96 MFMA].
// B (afc, 4 MB, L2-resident) never staged; A double-buffered (2x32 KB LDS).
// [R6-best configuration: 47 us/dispatch. Pipelining/occupancy variants R7-R9 all regressed.]
__global__ __launch_bounds__(256) void gemm1_mfma128(
    const __hip_bfloat16* __restrict__ Ah, const __hip_bfloat16* __restrict__ Al,  // x0sT h/l [4224][2048]
    const __hip_bfloat16* __restrict__ Bh, const __hip_bfloat16* __restrict__ Bl,  // afc h/l [256][2048]
    float* __restrict__ part)
{
    __shared__ __align__(16) __hip_bfloat16 S1[2][8192];   // A-h dbuf
    __shared__ __align__(16) __hip_bfloat16 S2[2][8192];   // A-l dbuf (64 KB total)

    const int K = N_NODES;
    int tid  = threadIdx.x;
    int wave = tid >> 6, lane = tid & 63;
    int quad = lane >> 4, lr = lane & 15;
    int wr = wave >> 1, wc = wave & 1;
    int mBase = blockIdx.y * 128;            // j rows
    int nBase = blockIdx.x * 128;            // c cols
    int k0base = blockIdx.z * (K / ZSPLIT);  // 256-wide K slice

    size_t offA[4]; int lo[4];
    #pragma unroll
    for (int ch = 0; ch < 4; ch++) {
        int cell = (wave * 4 + ch) * 64 + lane;
        int kb = cell >> 7, mm = cell & 127;
        offA[ch] = (size_t)(mBase + mm) * K + k0base + kb * 8;
        lo[ch] = (wave * 4 + ch) * 512;
    }

    f32x4 acc[4][4];
    #pragma unroll
    for (int i = 0; i < 4; i++)
        #pragma unroll
        for (int j = 0; j < 4; j++) { f32x4 z = {0.f,0.f,0.f,0.f}; acc[i][j] = z; }

    const short* Bh_ = (const short*)Bh;
    const short* Bl_ = (const short*)Bl;

    // prologue: stage k-slice 0 into buffer 0
    #pragma unroll
    for (int ch = 0; ch < 4; ch++) {
        gload_lds16(Ah + offA[ch], &S1[0][lo[ch]]);
        gload_lds16(Al + offA[ch], &S2[0][lo[ch]]);
    }
    __syncthreads();

    #pragma unroll 1
    for (int t = 0; t < 4; t++) {
        int cur = t & 1;

        // hoisted B-fragment loads for this k-slice (16 x 16B, L2 hits)
        s16x8 bh[2][4], bl[2][4];
        #pragma unroll
        for (int ks = 0; ks < 2; ks++) {
            int kb = ks * 4 + quad;
            #pragma unroll
            for (int j = 0; j < 4; j++) {
                size_t bo = (size_t)(nBase + wc * 64 + j * 16 + lr) * K + k0base + t * 64 + kb * 8;
                bh[ks][j] = *(const s16x8*)(Bh_ + bo);
                bl[ks][j] = *(const s16x8*)(Bl_ + bo);
            }
        }

        // async prefetch of next k-slice into the other buffer (completes by end barrier)
        if (t < 3) {
            #pragma unroll
            for (int ch = 0; ch < 4; ch++) {
                gload_lds16(Ah + offA[ch] + (t + 1) * 64, &S1[cur ^ 1][lo[ch]]);
                gload_lds16(Al + offA[ch] + (t + 1) * 64, &S2[cur ^ 1][lo[ch]]);
            }
        }

        const s16x8* AhV = (const s16x8*)S1[cur];
        const s16x8* AlV = (const s16x8*)S2[cur];
        #pragma unroll
        for (int ks = 0; ks < 2; ks++) {
            int kb = ks * 4 + quad;
            s16x8 ah[4], al[4];
            #pragma unroll
            for (int i = 0; i < 4; i++) {
                int idx = kb * 128 + wr * 64 + i * 16 + lr;
                ah[i] = AhV[idx]; al[i] = AlV[idx];
            }
            #pragma unroll
            for (int j = 0; j < 4; j++)
                #pragma unroll
                for (int i = 0; i < 4; i++) {
                    acc[i][j] = __builtin_amdgcn_mfma_f32_16x16x32_bf16(ah[i], bh[ks][j], acc[i][j], 0, 0, 0);
                    acc[i][j] = __builtin_amdgcn_mfma_f32_16x16x32_bf16(ah[i], bl[ks][j], acc[i][j], 0, 0, 0);
                    acc[i][j] = __builtin_amdgcn_mfma_f32_16x16x32_bf16(al[i], bh[ks][j], acc[i][j], 0, 0, 0);
                }
        }
        __syncthreads();
    }

    float* dst = part + (size_t)blockIdx.z * JSX * C_NODES;
    #pragma unroll
    for (int i = 0; i < 4; i++)
        #pragma unroll
        for (int j = 0; j < 4; j++)
            #pragma unroll
            for (int r = 0; r < 4; r++) {
                int row = mBase + wr * 64 + i * 16 + quad * 4 + r;
                int col = nBase + wc * 64 + j * 16 + lr;
                dst[(size_t)row * C_NODES + col] = acc[i][j][r];
            }
}

// reduce ZSPLIT split-K partials -> hi/lo bf16 pair
__global__ __launch_bounds__(256) void reduce_split(const float* __restrict__ part,
                                                    __hip_bfloat16* __restrict__ oh,
                                                    __hip_bfloat16* __restrict__ ol, int n)
{
    int stride = gridDim.x * 256;
    const size_t slice = (size_t)JSX * C_NODES;
    for (int i = blockIdx.x * 256 + threadIdx.x; i < n; i += stride) {
        float v = 0.f;
        #pragma unroll
        for (int s = 0; s < ZSPLIT; s++) v += part[s * slice + i];
        __hip_bfloat16 h = __float2bfloat16(v);
        oh[i] = h;
        ol[i] = __float2bfloat16(v - __bfloat162float(h));
    }
}

// ---------------- coarse GEMM: x1 = sigmoid(afct@x0fc) (K=256, 3-term split) ----------------
// M=2048(n) x N=4224(j), 128x128 tiles, grid (33,16).
// NO LDS / NO BARRIERS: A (afct, 2x1MB) and B (x0fcT, 2x2.2MB) are L2-RESIDENT (written just
// before by cvt/reduce), so direct global fragments see ~200cy L2 latency -- coverable by the
// 48-MFMA runs, unlike gemm1's HBM-cold case (R7). 8 k-steps of 32 fully unrolled.
// Output in BATCH-BLOCKED layout: x1B[j>>6][n][j&63]  (66 blocks of [2048][64]).
__global__ __launch_bounds__(256) void gemm_coarse(
    const __hip_bfloat16* __restrict__ Ah, const __hip_bfloat16* __restrict__ Al,  // afct h/l [2048][256]
    const __hip_bfloat16* __restrict__ Bh, const __hip_bfloat16* __restrict__ Bl,  // x0fcT h/l [4224][256]
    __hip_bfloat16* __restrict__ OutH, __hip_bfloat16* __restrict__ OutL)
{
    const int K = C_NODES;
    int tid  = threadIdx.x;
    int wave = tid >> 6, lane = tid & 63;
    int quad = lane >> 4, lr = lane & 15;
    int wr = wave >> 1, wc = wave & 1;
    int mBase = blockIdx.y * 128, nBase = blockIdx.x * 128;

    const short* Ah_ = (const short*)Ah;
    const short* Al_ = (const short*)Al;
    const short* Bh_ = (const short*)Bh;
    const short* Bl_ = (const short*)Bl;

    size_t aoff[4], boff[4];
    #pragma unroll
    for (int i = 0; i < 4; i++)
        aoff[i] = (size_t)(mBase + wr * 64 + i * 16 + lr) * K + quad * 8;
    #pragma unroll
    for (int j = 0; j < 4; j++)
        boff[j] = (size_t)(nBase + wc * 64 + j * 16 + lr) * K + quad * 8;

    f32x4 acc[4][4];
    #pragma unroll
    for (int i = 0; i < 4; i++)
        #pragma unroll
        for (int j = 0; j < 4; j++) { f32x4 z = {0.f,0.f,0.f,0.f}; acc[i][j] = z; }

    #pragma unroll
    for (int ks = 0; ks < 8; ks++) {        // 8 MFMA k-steps of 32 over K=256
        int ko = ks * 32;
        s16x8 ah[4], al[4], bh[4], bl[4];
        #pragma unroll
        for (int i = 0; i < 4; i++) {
            ah[i] = *(const s16x8*)(Ah_ + aoff[i] + ko);
            al[i] = *(const s16x8*)(Al_ + aoff[i] + ko);
        }
        #pragma unroll
        for (int j = 0; j < 4; j++) {
            bh[j] = *(const s16x8*)(Bh_ + boff[j] + ko);
            bl[j] = *(const s16x8*)(Bl_ + boff[j] + ko);
        }
        #pragma unroll
        for (int i = 0; i < 4; i++)
            #pragma unroll
            for (int j = 0; j < 4; j++) {
                acc[i][j] = __builtin_amdgcn_mfma_f32_16x16x32_bf16(ah[i], bh[j], acc[i][j], 0, 0, 0);
                acc[i][j] = __builtin_amdgcn_mfma_f32_16x16x32_bf16(ah[i], bl[j], acc[i][j], 0, 0, 0);
                acc[i][j] = __builtin_amdgcn_mfma_f32_16x16x32_bf16(al[i], bh[j], acc[i][j], 0, 0, 0);
            }
    }

    #pragma unroll
    for (int i = 0; i < 4; i++)
        #pragma unroll
        for (int j = 0; j < 4; j++)
            #pragma unroll
            for (int r = 0; r < 4; r++) {
                int row = mBase + wr * 64 + i * 16 + quad * 4 + r;
                int col = nBase + wc * 64 + j * 16 + lr;
                float v = sigmoidf_(acc[i][j][r]);
                size_t idx = (size_t)(col >> 6) * NU + (size_t)row * 64 + (col & 63);
                __hip_bfloat16 h = __float2bfloat16(v);
                OutH[idx] = h;
                OutL[idx] = __float2bfloat16(v - __bfloat162float(h));
            }
}

// ---------------- SpMM: x1B += adj @ X (f32 adj vals, bf16 X rows) ----------------
// 1D XCD-pinned grid: wgid<4096: jt = wgid&7 (all blocks of a j-tile on ONE XCD ->
// its 2MB X column slice stays L2-resident), nb = wgid>>3. wgid>=4096: jt=8 (input cols).
// Block = 4 waves, wave-per-node. CSR metadata staged in LDS (broadcast reads, addresses
// available early); gather loop unrolled 8 for deep VMEM pipelining.
__global__ __launch_bounds__(256) void spmm_add(
    const __hip_bfloat16* __restrict__ X,
    const unsigned short* __restrict__ cols,
    const float* __restrict__ vals,
    const int* __restrict__ nnz,
    __hip_bfloat16* __restrict__ OutH,
    __hip_bfloat16* __restrict__ OutL)
{
    __shared__ unsigned short colS[4 * CAP];
    __shared__ float          valS[4 * CAP];
    __shared__ int            cntS[4];

    int tid  = threadIdx.x;
    int wave = tid >> 6, lane = tid & 63;
    int wgid = blockIdx.x;
    int jt, nb;
    if (wgid < 4096) { jt = wgid & 7; nb = wgid >> 3; }
    else             { jt = 8;        nb = wgid - 4096; }
    int nBase = nb * 4;

    // stage CSR metadata for the block's 4 nodes (contiguous in cols/vals)
    if (tid < 4) cntS[tid] = nnz[nBase + tid];
    {
        const unsigned short* cpg = cols + (size_t)nBase * CAP;
        const float*          vpg = vals + (size_t)nBase * CAP;
        #pragma unroll
        for (int it = 0; it < 3; it++) {
            int idx = tid + it * 256;
            colS[idx] = cpg[idx];
            valS[idx] = vpg[idx];
        }
    }
    __syncthreads();

    int n   = nBase + wave;
    int cnt = cntS[wave];
    const unsigned short* cp = colS + wave * CAP;
    const float*          vp = valS + wave * CAP;
    const short* Xs = (const short*)X;

    if (jt < 8) {
        int j0 = jt * 512 + lane * 8;
        float acc[8];
        #pragma unroll
        for (int e = 0; e < 8; e++) acc[e] = 0.f;
        int i = 0;
        for (; i + 8 <= cnt; i += 8) {
            int   c[8]; float a[8];
            #pragma unroll
            for (int q = 0; q < 8; q++) { c[q] = cp[i + q]; a[q] = vp[i + q]; }
            s16x8 xv[8];
            #pragma unroll
            for (int q = 0; q < 8; q++)
                xv[q] = *(const s16x8*)(Xs + (size_t)c[q] * XSTR + j0);
            #pragma unroll
            for (int q = 0; q < 8; q++)
                #pragma unroll
                for (int e = 0; e < 8; e++) acc[e] += a[q] * bfs2f(xv[q][e]);
        }
        for (; i < cnt; i++) {
            int c = cp[i]; float a = vp[i];
            s16x8 xv = *(const s16x8*)(Xs + (size_t)c * XSTR + j0);
            #pragma unroll
            for (int e = 0; e < 8; e++) acc[e] += a * bfs2f(xv[e]);
        }
        // blocked: j = jt*512 + lane*8 -> block = jt*8 + (lane>>3), u = (lane&7)*8
        size_t o = (size_t)(jt * 8 + (lane >> 3)) * NU + (size_t)n * 64 + (lane & 7) * 8;
        s16x8 h = *(const s16x8*)((const short*)OutH + o);
        s16x8 l = *(const s16x8*)((const short*)OutL + o);
        s16x8 nh, nl;
        #pragma unroll
        for (int e = 0; e < 8; e++) {
            float v = bfs2f(h[e]) + bfs2f(l[e]) + acc[e];
            short hh = f2bfs(v);
            nh[e] = hh;
            nl[e] = f2bfs(v - bfs2f(hh));
        }
        *(s16x8*)((short*)OutH + o) = nh;
        *(s16x8*)((short*)OutL + o) = nl;
    } else {
        float acc = 0.f;
        int i = 0;
        for (; i + 8 <= cnt; i += 8) {
            int   c[8]; float a[8];
            #pragma unroll
            for (int q = 0; q < 8; q++) { c[q] = cp[i + q]; a[q] = vp[i + q]; }
            short xv[8];
            #pragma unroll
            for (int q = 0; q < 8; q++) xv[q] = Xs[(size_t)c[q] * XSTR + 4096 + lane];
            #pragma unroll
            for (int q = 0; q < 8; q++) acc += a[q] * bfs2f(xv[q]);
        }
        for (; i < cnt; i++) {
            int c = cp[i]; float a = vp[i];
            acc += a * bfs2f(Xs[(size_t)c * XSTR + 4096 + lane]);
        }
        size_t o = (size_t)64 * NU + (size_t)n * 64 + lane;   // block 64, u = lane(=b)
        float v = bfs2f(((const short*)OutH)[o]) + bfs2f(((const short*)OutL)[o]) + acc;
        short hh = f2bfs(v);
        ((short*)OutH)[o] = hh;
        ((short*)OutL)[o] = f2bfs(v - bfs2f(hh));
    }
}

// ---------------- head1 (split MFMA): gates = x1s @ w0T + w0_row0*xin + b0 ----------------
// x1B blocked input: A-fragments loaded DIRECTLY from global (coalesced 64B segments).
// W fragments direct from global (L1-resident). LDS only for the x0sT transpose (XOR-swizzled).
// launch_bounds (256,3): VGPR cap 170 so the per-i state preloads batch into one load cluster.
__global__ __launch_bounds__(256, 3) void head1_mfma(
    const __hip_bfloat16* __restrict__ x1h, const __hip_bfloat16* __restrict__ x1l,
    const __hip_bfloat16* __restrict__ Wh, const __hip_bfloat16* __restrict__ Wl,
    const float* __restrict__ w0, const float* __restrict__ b0,
    const float* __restrict__ state,
    __hip_bfloat16* __restrict__ xh, __hip_bfloat16* __restrict__ xl,
    __hip_bfloat16* __restrict__ u_buf,
    __hip_bfloat16* __restrict__ Xout)
{
    __shared__ __align__(16) short trH[8192];   // [64 o][128 n], n XOR-swizzled by (o&15)<<3
    __shared__ __align__(16) short trL[8192];
    __shared__ float xinS[128];

    int n0 = blockIdx.x * 128;
    int b  = blockIdx.y;
    int tid = threadIdx.x;
    int wave = tid >> 6, lane = tid & 63;
    int quad = lane >> 4, lr = lane & 15;
    int wr = wave >> 1, wc = wave & 1;

    if (tid < 128) {
        size_t o = (size_t)64 * NU + (size_t)(n0 + tid) * 64 + b;
        xinS[tid] = __bfloat162float(x1h[o]) + __bfloat162float(x1l[o]);
    }

    f32x4 acc[4][4];
    #pragma unroll
    for (int i = 0; i < 4; i++)
        #pragma unroll
        for (int j = 0; j < 4; j++) { f32x4 z = {0.f,0.f,0.f,0.f}; acc[i][j] = z; }

    const short* Xh = (const short*)x1h + (size_t)b * NU;
    const short* Xl = (const short*)x1l + (size_t)b * NU;
    const short* Wh_ = (const short*)Wh;
    const short* Wl_ = (const short*)Wl;

    #pragma unroll
    for (int ks = 0; ks < 2; ks++) {
        s16x8 ah[4], al[4];
        #pragma unroll
        for (int i = 0; i < 4; i++) {
            size_t off = (size_t)(n0 + wr * 64 + i * 16 + lr) * 64 + ks * 32 + quad * 8;
            ah[i] = *(const s16x8*)(Xh + off);
            al[i] = *(const s16x8*)(Xl + off);
        }
        #pragma unroll
        for (int j = 0; j < 4; j++) {
            size_t wo = ((size_t)(ks * 4 + quad) * 128 + wc * 64 + j * 16 + lr) * 8;
            s16x8 bh = *(const s16x8*)(Wh_ + wo);
            s16x8 bl = *(const s16x8*)(Wl_ + wo);
            #pragma unroll
            for (int i = 0; i < 4; i++) {
                acc[i][j] = __builtin_amdgcn_mfma_f32_16x16x32_bf16(ah[i], bh, acc[i][j], 0, 0, 0);
                acc[i][j] = __builtin_amdgcn_mfma_f32_16x16x32_bf16(ah[i], bl, acc[i][j], 0, 0, 0);
                acc[i][j] = __builtin_amdgcn_mfma_f32_16x16x32_bf16(al[i], bh, acc[i][j], 0, 0, 0);
            }
        }
    }
    __syncthreads();   // xinS ready

    if (wc == 0) {
        #pragma unroll
        for (int i = 0; i < 4; i++) {
            // batched preload: 16 independent state loads in flight, then compute
            float sv[4][4];
            #pragma unroll
            for (int j = 0; j < 4; j++)
                #pragma unroll
                for (int r = 0; r < 4; r++)
                    sv[j][r] = state[(size_t)b * NU
                                     + (size_t)(n0 + wr * 64 + i * 16 + quad * 4 + r) * 64
                                     + j * 16 + lr];
            #pragma unroll
            for (int j = 0; j < 4; j++)
                #pragma unroll
                for (int r = 0; r < 4; r++) {
                    int n_loc = wr * 64 + i * 16 + quad * 4 + r;
                    int o = j * 16 + lr;
                    float g = acc[i][j][r] + w0[o] * xinS[n_loc] + b0[o];
                    float sg = sigmoidf_(g);
                    float rs = sg * sv[j][r];
                    short h = f2bfs(rs);
                    int sw = n_loc ^ ((o & 15) << 3);
                    trH[o * 128 + sw] = h;
                    trL[o * 128 + sw] = f2bfs(rs - bfs2f(h));
                    ((short*)Xout)[(size_t)(n0 + n_loc) * XSTR + b * 64 + o] = h;
                }
        }
    } else {
        #pragma unroll
        for (int i = 0; i < 4; i++)
            #pragma unroll
            for (int j = 0; j < 4; j++)
                #pragma unroll
                for (int r = 0; r < 4; r++) {
                    int n_loc = wr * 64 + i * 16 + quad * 4 + r;
                    int o = 64 + j * 16 + lr;
                    float g = acc[i][j][r] + w0[o] * xinS[n_loc] + b0[o];
                    float sg = sigmoidf_(g);
                    u_buf[(size_t)b * NU + (size_t)(n0 + n_loc) * 64 + (o - 64)] = __float2bfloat16(sg);
                }
    }
    __syncthreads();

    {
        int row = tid >> 2, seg = tid & 3;
        int xorv = (row & 15) << 3;
        short* dh = (short*)xh + (size_t)(b * 64 + row) * N_NODES + n0 + seg * 32;
        short* dl = (short*)xl + (size_t)(b * 64 + row) * N_NODES + n0 + seg * 32;
        #pragma unroll
        for (int q = 0; q < 4; q++) {
            int src = row * 128 + ((seg * 32 + q * 8) ^ xorv);
            *(uint4*)(dh + q * 8) = *(const uint4*)(trH + src);
            *(uint4*)(dl + q * 8) = *(const uint4*)(trL + src);
        }
    }
}

// ---------------- head2 (split MFMA): out = u*s + (1-u)*tanh(x1s@w1T + w1_row0*xin + b1) ----------------
// A-fragments + W fragments direct from global; no LDS except xinS.
// launch_bounds (256,3): room to batch ALL 32 state + 32 u_buf loads before the tanh loop.
__global__ __launch_bounds__(256, 3) void head2_mfma(
    const __hip_bfloat16* __restrict__ x1h, const __hip_bfloat16* __restrict__ x1l,
    const __hip_bfloat16* __restrict__ Wh, const __hip_bfloat16* __restrict__ Wl,
    const float* __restrict__ w1, const float* __restrict__ b1,
    const float* __restrict__ state, const __hip_bfloat16* __restrict__ u_buf,
    float* __restrict__ out)
{
    __shared__ float xinS[128];

    int n0 = blockIdx.x * 128;
    int b  = blockIdx.y;
    int tid = threadIdx.x;
    int wave = tid >> 6, lane = tid & 63;
    int quad = lane >> 4, lr = lane & 15;

    if (tid < 128) {
        size_t o = (size_t)64 * NU + (size_t)(n0 + tid) * 64 + b;
        xinS[tid] = __bfloat162float(x1h[o]) + __bfloat162float(x1l[o]);
    }

    f32x4 acc[2][4];
    #pragma unroll
    for (int i = 0; i < 2; i++)
        #pragma unroll
        for (int j = 0; j < 4; j++) { f32x4 z = {0.f,0.f,0.f,0.f}; acc[i][j] = z; }

    const short* Xh = (const short*)x1h + (size_t)b * NU;
    const short* Xl = (const short*)x1l + (size_t)b * NU;
    const short* Wh_ = (const short*)Wh;
    const short* Wl_ = (const short*)Wl;

    #pragma unroll
    for (int ks = 0; ks < 2; ks++) {
        s16x8 ah[2], al[2];
        #pragma unroll
        for (int i = 0; i < 2; i++) {
            size_t off = (size_t)(n0 + wave * 32 + i * 16 + lr) * 64 + ks * 32 + quad * 8;
            ah[i] = *(const s16x8*)(Xh + off);
            al[i] = *(const s16x8*)(Xl + off);
        }
        #pragma unroll
        for (int j = 0; j < 4; j++) {
            size_t wo = ((size_t)(ks * 4 + quad) * 64 + j * 16 + lr) * 8;
            s16x8 bh = *(const s16x8*)(Wh_ + wo);
            s16x8 bl = *(const s16x8*)(Wl_ + wo);
            #pragma unroll
            for (int i = 0; i < 2; i++) {
                acc[i][j] = __builtin_amdgcn_mfma_f32_16x16x32_bf16(ah[i], bh, acc[i][j], 0, 0, 0);
                acc[i][j] = __builtin_amdgcn_mfma_f32_16x16x32_bf16(ah[i], bl, acc[i][j], 0, 0, 0);
                acc[i][j] = __builtin_amdgcn_mfma_f32_16x16x32_bf16(al[i], bh, acc[i][j], 0, 0, 0);
            }
        }
    }
    __syncthreads();   // xinS ready

    // batched preload of state + u (64 independent loads in flight)
    float sv[2][4][4];
    float uv[2][4][4];
    #pragma unroll
    for (int i = 0; i < 2; i++)
        #pragma unroll
        for (int j = 0; j < 4; j++)
            #pragma unroll
            for (int r = 0; r < 4; r++) {
                size_t sidx = (size_t)b * NU
                            + (size_t)(n0 + wave * 32 + i * 16 + quad * 4 + r) * 64
                            + j * 16 + lr;
                sv[i][j][r] = state[sidx];
                uv[i][j][r] = __bfloat162float(u_buf[sidx]);
            }

    #pragma unroll
    for (int i = 0; i < 2; i++)
        #pragma unroll
        for (int j = 0; j < 4; j++)
            #pragma unroll
            for (int r = 0; r < 4; r++) {
                int n_loc = wave * 32 + i * 16 + quad * 4 + r;
                int o = j * 16 + lr;
                float g = acc[i][j][r] + w1[o] * xinS[n_loc] + b1[o];
                float c = tanhf(g);
                size_t sidx = (size_t)b * NU + (size_t)(n0 + n_loc) * 64 + o;
                float ug = uv[i][j][r];
                float svv = sv[i][j][r];
                out[sidx] = ug * svv + (1.0f - ug) * c;
            }
}

extern "C" void kernel_launch(void* const* d_in, const int* in_sizes, int n_in,
                              void* d_out, int out_size, void* d_ws, size_t ws_size,
                              hipStream_t stream)
{
    const float* inputs = (const float*)d_in[0];
    const float* state  = (const float*)d_in[1];
    const float* adj    = (const float*)d_in[2];
    // d_in[3] = adj1 : unused (discarded outfc path)
    const float* afc    = (const float*)d_in[4];   // [C][N]
    const float* afct   = (const float*)d_in[5];   // [N][C]
    const float* w0     = (const float*)d_in[6];
    const float* b0     = (const float*)d_in[7];
    const float* w1     = (const float*)d_in[8];
    const float* b1     = (const float*)d_in[9];
    // d_in[10..13]: unused

    float* out = (float*)d_out;

    char* p = (char*)d_ws;
    __hip_bfloat16* afc_h    = (__hip_bfloat16*)p; p += (size_t)C_NODES * N_NODES * 2;
    __hip_bfloat16* afc_l    = (__hip_bfloat16*)p; p += (size_t)C_NODES * N_NODES * 2;
    __hip_bfloat16* afct_h   = (__hip_bfloat16*)p; p += (size_t)N_NODES * C_NODES * 2;
    __hip_bfloat16* afct_l   = (__hip_bfloat16*)p; p += (size_t)N_NODES * C_NODES * 2;
    __hip_bfloat16* w0T_h    = (__hip_bfloat16*)p; p += 8192 * 2;
    __hip_bfloat16* w0T_l    = (__hip_bfloat16*)p; p += 8192 * 2;
    __hip_bfloat16* w1T_h    = (__hip_bfloat16*)p; p += 4096 * 2;
    __hip_bfloat16* w1T_l    = (__hip_bfloat16*)p; p += 4096 * 2;
    __hip_bfloat16* x0sT_h   = (__hip_bfloat16*)p; p += (size_t)JSX * N_NODES * 2;       // 17.3 MB
    __hip_bfloat16* x0sT_l   = (__hip_bfloat16*)p; p += (size_t)JSX * N_NODES * 2;
    __hip_bfloat16* x0fcT_h  = (__hip_bfloat16*)p; p += (size_t)JSX * C_NODES * 2;       // 2.16 MB
    __hip_bfloat16* x0fcT_l  = (__hip_bfloat16*)p; p += (size_t)JSX * C_NODES * 2;
    // part (ZSPLIT x JSX x 256 f32 = 34.6 MB) ALIASES x1B_h/x1B_l (34.6 MB):
    // part is live only gemm1->reduce; x1B is fully rewritten by gemm_coarse afterwards.
    float*          part     = (float*)p;
    __hip_bfloat16* x1B_h    = (__hip_bfloat16*)p; p += (size_t)66 * NU * 2;             // 17.3 MB (batch-blocked)
    __hip_bfloat16* x1B_l    = (__hip_bfloat16*)p; p += (size_t)66 * NU * 2;
    __hip_bfloat16* u_buf    = (__hip_bfloat16*)p; p += (size_t)BATCH * NU * 2;          // 16.78 MB
    __hip_bfloat16* X        = (__hip_bfloat16*)p; p += (size_t)N_NODES * XSTR * 2;      // 17.04 MB
    unsigned short* csr_cols = (unsigned short*)p; p += (size_t)N_NODES * CAP * 2;       // 0.79 MB
    float*          csr_vals = (float*)p;          p += (size_t)N_NODES * CAP * 4;       // 1.57 MB
    int*            csr_nnz  = (int*)p;            p += (size_t)N_NODES * 4;
    // total ~114 MB

    dim3 blk(256);

    // ---- once: converts + CSR + extended-row setup ----
    cvt_split<<<256,  blk, 0, stream>>>(afc,  afc_h,  afc_l,  C_NODES * N_NODES);
    cvt_split<<<256,  blk, 0, stream>>>(afct, afct_h, afct_l, N_NODES * C_NODES);
    cvt_w    <<<32,   blk, 0, stream>>>(w0, w1, w0T_h, w0T_l, w1T_h, w1T_l);
    setup_ext<<<128,  blk, 0, stream>>>(inputs, x0sT_h, x0sT_l, x0fcT_h, x0fcT_l, X);
    build_csr<<<512,  blk, 0, stream>>>(adj, csr_cols, csr_vals, csr_nnz);

    // ---- pass 1 ----
    build_x0sT<<<dim3(32, 64), blk, 0, stream>>>(state, x0sT_h, x0sT_l, X);
    gemm1_mfma128<<<dim3(2, 33, ZSPLIT), blk, 0, stream>>>(x0sT_h, x0sT_l, afc_h, afc_l, part);
    reduce_split<<<1024, blk, 0, stream>>>(part, x0fcT_h, x0fcT_l, NX * C_NODES);
    gemm_coarse<<<dim3(33, 16), blk, 0, stream>>>(afct_h, afct_l, x0fcT_h, x0fcT_l, x1B_h, x1B_l);
    spmm_add<<<dim3(4608), blk, 0, stream>>>(X, csr_cols, csr_vals, csr_nnz, x1B_h, x1B_l);
    head1_mfma<<<dim3(16, 64), blk, 0, stream>>>(x1B_h, x1B_l, w0T_h, w0T_l, w0, b0,
                                                 state, x0sT_h, x0sT_l, u_buf, X);

    // ---- pass 2 (x0sT/X state rows now hold r*state; input rows unchanged) ----
    gemm1_mfma128<<<dim3(2, 33, ZSPLIT), blk, 0, stream>>>(x0sT_h, x0sT_l, afc_h, afc_l, part);
    reduce_split<<<1024, blk, 0, stream>>>(part, x0fcT_h, x0fcT_l, NX * C_NODES);
    gemm_coarse<<<dim3(33, 16), blk, 0, stream>>>(afct_h, afct_l, x0fcT_h, x0fcT_l, x1B_h, x1B_l);
    spmm_add<<<dim3(4608), blk, 0, stream>>>(X, csr_cols, csr_vals, csr_nnz, x1B_h, x1B_l);
    head2_mfma<<<dim3(16, 64), blk, 0, stream>>>(x1B_h, x1B_l, w1T_h, w1T_l, w1, b1,
                                                 state, u_buf, out);
}

// Round 11
// 458.100 us; speedup vs baseline: 1.0692x; 1.0510x over previous
//
#include <hip/hip_runtime.h>
#include <hip/hip_bf16.h>
#include <math.h>

#define N_NODES 2048
#define C_NODES 256
#define BATCH   64
#define UNITS   64
#define JS      4096                // state-part columns: j = b*64+u
#define NX      4160                // + 64 input-channel columns
#define JSX     4224                // padded to 33 x 128 tiles (66 x 64-blocks)
#define NU      131072              // N_NODES * UNITS
#define XSTR    4160                // X row stride (state cols + input cols)
#define CAP     192                 // max nnz per adj row (mean ~33)
#define ZSPLIT  8                   // gemm1 split-K factor

typedef short  s16x8 __attribute__((ext_vector_type(8)));   // 8 bf16 in 4 VGPRs
typedef float  f32x4 __attribute__((ext_vector_type(4)));

__device__ __forceinline__ float sigmoidf_(float x) { return 1.0f / (1.0f + __expf(-x)); }

__device__ __forceinline__ float bfs2f(short s) {
    union { float f; unsigned u; } w; w.u = ((unsigned)(unsigned short)s) << 16; return w.f;
}
__device__ __forceinline__ short f2bfs(float f) {
    __hip_bfloat16 h = __float2bfloat16(f);
    short s; __builtin_memcpy(&s, &h, 2); return s;
}

__device__ __forceinline__ void gload_lds16(const void* g, void* l) {
    __builtin_amdgcn_global_load_lds(
        (const __attribute__((address_space(1))) void*)g,
        (__attribute__((address_space(3))) void*)l, 16, 0, 0);
}

// ---------------- converts ----------------
__global__ __launch_bounds__(256) void cvt_split(const float* __restrict__ s,
                                                 __hip_bfloat16* __restrict__ dh,
                                                 __hip_bfloat16* __restrict__ dl, int n)
{
    int stride = gridDim.x * 256;
    for (int i = blockIdx.x * 256 + threadIdx.x; i < n; i += stride) {
        float v = s[i];
        __hip_bfloat16 h = __float2bfloat16(v);
        dh[i] = h;
        dl[i] = __float2bfloat16(v - __bfloat162float(h));
    }
}

// w0[65][128], w1[65][64] -> blocked transposed bf16 h/l: cell (c*O+o), elem jj = w[(1+c*8+jj)*O + o]
__global__ __launch_bounds__(256) void cvt_w(const float* __restrict__ w0,
                                             const float* __restrict__ w1,
                                             __hip_bfloat16* __restrict__ w0h, __hip_bfloat16* __restrict__ w0l,
                                             __hip_bfloat16* __restrict__ w1h, __hip_bfloat16* __restrict__ w1l)
{
    int stride = gridDim.x * 256;
    for (int e = blockIdx.x * 256 + threadIdx.x; e < 8192 + 4096; e += stride) {
        if (e < 8192) {  // w0T: O=128
            int jj = e & 7, cell = e >> 3;
            int o = cell & 127, c = cell >> 7;
            float v = w0[(size_t)(1 + c * 8 + jj) * 128 + o];
            __hip_bfloat16 h = __float2bfloat16(v);
            w0h[e] = h; w0l[e] = __float2bfloat16(v - __bfloat162float(h));
        } else {         // w1T: O=64
            int e2 = e - 8192;
            int jj = e2 & 7, cell = e2 >> 3;
            int o = cell & 63, c = cell >> 6;
            float v = w1[(size_t)(1 + c * 8 + jj) * 64 + o];
            __hip_bfloat16 h = __float2bfloat16(v);
            w1h[e2] = h; w1l[e2] = __float2bfloat16(v - __bfloat162float(h));
        }
    }
}

// once: x0sT rows 4096..4159 = inputs (hi/lo); X input cols; zero rows 4160..4223 of x0sT/x0fcT
__global__ __launch_bounds__(256) void setup_ext(
    const float* __restrict__ inputs,
    __hip_bfloat16* __restrict__ xh, __hip_bfloat16* __restrict__ xl,
    __hip_bfloat16* __restrict__ fh, __hip_bfloat16* __restrict__ fl,
    __hip_bfloat16* __restrict__ X)
{
    int blk = blockIdx.x;
    if (blk < 64) {
        int b = blk;
        for (int n = threadIdx.x; n < N_NODES; n += 256) {
            float v = inputs[(size_t)b * N_NODES + n];
            __hip_bfloat16 h = __float2bfloat16(v);
            size_t o = (size_t)(JS + b) * N_NODES + n;
            xh[o] = h;
            xl[o] = __float2bfloat16(v - __bfloat162float(h));
            X[(size_t)n * XSTR + 4096 + b] = h;   // input cols of X (once; never rewritten)
        }
    } else {
        int r = NX + (blk - 64);   // 4160..4223
        __hip_bfloat16 z = __float2bfloat16(0.0f);
        for (int n = threadIdx.x; n < N_NODES; n += 256) {
            size_t o = (size_t)r * N_NODES + n;
            xh[o] = z; xl[o] = z;
        }
        for (int c = threadIdx.x; c < C_NODES; c += 256) {
            size_t o = (size_t)r * C_NODES + c;
            fh[o] = z; fl[o] = z;
        }
    }
}

// ---------------- adj -> CSR (once). One wave per row, ballot compaction ----------------
__global__ __launch_bounds__(256) void build_csr(
    const float* __restrict__ adj,
    unsigned short* __restrict__ cols,
    float* __restrict__ vals,
    int* __restrict__ nnz)
{
    int row  = blockIdx.x * 4 + (threadIdx.x >> 6);
    int lane = threadIdx.x & 63;
    const float* a = adj + (size_t)row * N_NODES;
    int base = 0;
    for (int k0 = 0; k0 < N_NODES; k0 += 64) {
        float v = a[k0 + lane];
        unsigned long long m = __ballot(v != 0.0f);
        if (v != 0.0f) {
            int pos = base + __popcll(m & ((1ull << lane) - 1));
            if (pos < CAP) {
                cols[(size_t)row * CAP + pos] = (unsigned short)(k0 + lane);
                vals[(size_t)row * CAP + pos] = v;
            }
        }
        base += __popcll(m);
    }
    if (lane == 0) nnz[row] = base < CAP ? base : CAP;
}

// pass-1 x0sT build: state[b][n*64+u] -> x0sT_h/l[(b*64+u)][n]; also X[n][b*64+u] = bf16(state)
__global__ __launch_bounds__(256) void build_x0sT(const float* __restrict__ st,
                                                  __hip_bfloat16* __restrict__ xh,
                                                  __hip_bfloat16* __restrict__ xl,
                                                  __hip_bfloat16* __restrict__ X)
{
    __shared__ float Ls[64 * 65];
    int n0 = blockIdx.x * 64;
    int b  = blockIdx.y;
    int t  = threadIdx.x;
    #pragma unroll
    for (int it = 0; it < 16; it++) {
        int idx = t + it * 256;
        int i = idx >> 6, u = idx & 63;
        float v = st[(size_t)b * NU + (size_t)(n0 + i) * 64 + u];
        Ls[i * 65 + u] = v;
        X[(size_t)(n0 + i) * XSTR + b * 64 + u] = __float2bfloat16(v);
    }
    __syncthreads();
    #pragma unroll
    for (int it = 0; it < 16; it++) {
        int idx = t + it * 256;
        int u = idx >> 6, i = idx & 63;
        float v = Ls[i * 65 + u];
        __hip_bfloat16 h = __float2bfloat16(v);
        size_t o = (size_t)(b * 64 + u) * N_NODES + n0 + i;
        xh[o] = h;
        xl[o] = __float2bfloat16(v - __bfloat162float(h));
    }
}

// ---------------- GEMM1 (coarse projection, split-K): part[z] = x0sT_ext @ afc^T ----------------
// Out[j][c], M=4224, N=256, K=2048; 128x128 tiles; 3-term split. grid (2, 33, ZSPLIT).
// Per K-iteration: [hoisted B-frag global loads (issued first => waited first)]
// [async A-stage of NEXT slice into dbuf (drains at end barrier)] [LDS reads + 96 MFMA].
// B (afc, 4 MB, L2-resident) never staged; A double-buffered (2x32 KB LDS).
// [R6-best configuration. Variants tried and REGRESSED: no-LDS direct frags (R7, HBM-cold
//  latency), reg-dbuf pipeline (R8, compiler re-sinks), 64x128 occupancy tile (R9).]
__global__ __launch_bounds__(256) void gemm1_mfma128(
    const __hip_bfloat16* __restrict__ Ah, const __hip_bfloat16* __restrict__ Al,  // x0sT h/l [4224][2048]
    const __hip_bfloat16* __restrict__ Bh, const __hip_bfloat16* __restrict__ Bl,  // afc h/l [256][2048]
    float* __restrict__ part)
{
    __shared__ __align__(16) __hip_bfloat16 S1[2][8192];   // A-h dbuf
    __shared__ __align__(16) __hip_bfloat16 S2[2][8192];   // A-l dbuf (64 KB total)

    const int K = N_NODES;
    int tid  = threadIdx.x;
    int wave = tid >> 6, lane = tid & 63;
    int quad = lane >> 4, lr = lane & 15;
    int wr = wave >> 1, wc = wave & 1;
    int mBase = blockIdx.y * 128;            // j rows
    int nBase = blockIdx.x * 128;            // c cols
    int k0base = blockIdx.z * (K / ZSPLIT);  // 256-wide K slice

    size_t offA[4]; int lo[4];
    #pragma unroll
    for (int ch = 0; ch < 4; ch++) {
        int cell = (wave * 4 + ch) * 64 + lane;
        int kb = cell >> 7, mm = cell & 127;
        offA[ch] = (size_t)(mBase + mm) * K + k0base + kb * 8;
        lo[ch] = (wave * 4 + ch) * 512;
    }

    f32x4 acc[4][4];
    #pragma unroll
    for (int i = 0; i < 4; i++)
        #pragma unroll
        for (int j = 0; j < 4; j++) { f32x4 z = {0.f,0.f,0.f,0.f}; acc[i][j] = z; }

    const short* Bh_ = (const short*)Bh;
    const short* Bl_ = (const short*)Bl;

    // prologue: stage k-slice 0 into buffer 0
    #pragma unroll
    for (int ch = 0; ch < 4; ch++) {
        gload_lds16(Ah + offA[ch], &S1[0][lo[ch]]);
        gload_lds16(Al + offA[ch], &S2[0][lo[ch]]);
    }
    __syncthreads();

    #pragma unroll 1
    for (int t = 0; t < 4; t++) {
        int cur = t & 1;

        // hoisted B-fragment loads for this k-slice (16 x 16B, L2 hits)
        s16x8 bh[2][4], bl[2][4];
        #pragma unroll
        for (int ks = 0; ks < 2; ks++) {
            int kb = ks * 4 + quad;
            #pragma unroll
            for (int j = 0; j < 4; j++) {
                size_t bo = (size_t)(nBase + wc * 64 + j * 16 + lr) * K + k0base + t * 64 + kb * 8;
                bh[ks][j] = *(const s16x8*)(Bh_ + bo);
                bl[ks][j] = *(const s16x8*)(Bl_ + bo);
            }
        }

        // async prefetch of next k-slice into the other buffer (completes by end barrier)
        if (t < 3) {
            #pragma unroll
            for (int ch = 0; ch < 4; ch++) {
                gload_lds16(Ah + offA[ch] + (t + 1) * 64, &S1[cur ^ 1][lo[ch]]);
                gload_lds16(Al + offA[ch] + (t + 1) * 64, &S2[cur ^ 1][lo[ch]]);
            }
        }

        const s16x8* AhV = (const s16x8*)S1[cur];
        const s16x8* AlV = (const s16x8*)S2[cur];
        #pragma unroll
        for (int ks = 0; ks < 2; ks++) {
            int kb = ks * 4 + quad;
            s16x8 ah[4], al[4];
            #pragma unroll
            for (int i = 0; i < 4; i++) {
                int idx = kb * 128 + wr * 64 + i * 16 + lr;
                ah[i] = AhV[idx]; al[i] = AlV[idx];
            }
            #pragma unroll
            for (int j = 0; j < 4; j++)
                #pragma unroll
                for (int i = 0; i < 4; i++) {
                    acc[i][j] = __builtin_amdgcn_mfma_f32_16x16x32_bf16(ah[i], bh[ks][j], acc[i][j], 0, 0, 0);
                    acc[i][j] = __builtin_amdgcn_mfma_f32_16x16x32_bf16(ah[i], bl[ks][j], acc[i][j], 0, 0, 0);
                    acc[i][j] = __builtin_amdgcn_mfma_f32_16x16x32_bf16(al[i], bh[ks][j], acc[i][j], 0, 0, 0);
                }
        }
        __syncthreads();
    }

    float* dst = part + (size_t)blockIdx.z * JSX * C_NODES;
    #pragma unroll
    for (int i = 0; i < 4; i++)
        #pragma unroll
        for (int j = 0; j < 4; j++)
            #pragma unroll
            for (int r = 0; r < 4; r++) {
                int row = mBase + wr * 64 + i * 16 + quad * 4 + r;
                int col = nBase + wc * 64 + j * 16 + lr;
                dst[(size_t)row * C_NODES + col] = acc[i][j][r];
            }
}

// reduce ZSPLIT split-K partials -> hi/lo bf16 pair
__global__ __launch_bounds__(256) void reduce_split(const float* __restrict__ part,
                                                    __hip_bfloat16* __restrict__ oh,
                                                    __hip_bfloat16* __restrict__ ol, int n)
{
    int stride = gridDim.x * 256;
    const size_t slice = (size_t)JSX * C_NODES;
    for (int i = blockIdx.x * 256 + threadIdx.x; i < n; i += stride) {
        float v = 0.f;
        #pragma unroll
        for (int s = 0; s < ZSPLIT; s++) v += part[s * slice + i];
        __hip_bfloat16 h = __float2bfloat16(v);
        oh[i] = h;
        ol[i] = __float2bfloat16(v - __bfloat162float(h));
    }
}

// ---------------- coarse GEMM: x1 = sigmoid(afct@x0fc) (K=256, 3-term split) ----------------
// M=2048(n) x N=4224(j), 128x128 tiles, grid (33,16). LDS-staged (R10's no-LDS variant
// REGRESSED: streaming x1B writes evict the input panels from L2 -> FETCH 27->43 MB).
// Output in BATCH-BLOCKED layout: x1B[j>>6][n][j&63]  (66 blocks of [2048][64]).
__global__ __launch_bounds__(256, 2) void gemm_coarse(
    const __hip_bfloat16* __restrict__ Ah, const __hip_bfloat16* __restrict__ Al,  // afct h/l [2048][256]
    const __hip_bfloat16* __restrict__ Bh, const __hip_bfloat16* __restrict__ Bl,  // x0fcT h/l [4224][256]
    __hip_bfloat16* __restrict__ OutH, __hip_bfloat16* __restrict__ OutL)
{
    __shared__ __align__(16) __hip_bfloat16 S1[8192];
    __shared__ __align__(16) __hip_bfloat16 S2[8192];
    __shared__ __align__(16) __hip_bfloat16 S3[8192];
    __shared__ __align__(16) __hip_bfloat16 S4[8192];   // 64 KB

    int tid  = threadIdx.x;
    int wave = tid >> 6, lane = tid & 63;
    int quad = lane >> 4, lr = lane & 15;
    int wr = wave >> 1, wc = wave & 1;
    int mBase = blockIdx.y * 128, nBase = blockIdx.x * 128;

    int cellkb[4], cellmm[4];
    #pragma unroll
    for (int ch = 0; ch < 4; ch++) {
        int cell = (wave * 4 + ch) * 64 + lane;
        cellkb[ch] = cell >> 7;
        cellmm[ch] = cell & 127;
    }

    f32x4 acc[4][4];
    #pragma unroll
    for (int i = 0; i < 4; i++)
        #pragma unroll
        for (int j = 0; j < 4; j++) { f32x4 z = {0.f,0.f,0.f,0.f}; acc[i][j] = z; }

    for (int k0 = 0; k0 < C_NODES; k0 += 64) {
        #pragma unroll
        for (int ch = 0; ch < 4; ch++) {
            size_t offA = (size_t)(mBase + cellmm[ch]) * C_NODES + k0 + cellkb[ch] * 8;
            size_t offB = (size_t)(nBase + cellmm[ch]) * C_NODES + k0 + cellkb[ch] * 8;
            int lo = (wave * 4 + ch) * 512;
            gload_lds16(Ah + offA, S1 + lo);
            gload_lds16(Al + offA, S2 + lo);
            gload_lds16(Bh + offB, S3 + lo);
            gload_lds16(Bl + offB, S4 + lo);
        }
        __syncthreads();
        const s16x8* AhV = (const s16x8*)S1;
        const s16x8* AlV = (const s16x8*)S2;
        const s16x8* BhV = (const s16x8*)S3;
        const s16x8* BlV = (const s16x8*)S4;
        #pragma unroll
        for (int ks = 0; ks < 2; ks++) {
            int kb = ks * 4 + quad;
            s16x8 ah[4], al[4], bh[4], bl[4];
            #pragma unroll
            for (int i = 0; i < 4; i++) {
                int idx = kb * 128 + wr * 64 + i * 16 + lr;
                ah[i] = AhV[idx]; al[i] = AlV[idx];
            }
            #pragma unroll
            for (int j = 0; j < 4; j++) {
                int idx = kb * 128 + wc * 64 + j * 16 + lr;
                bh[j] = BhV[idx]; bl[j] = BlV[idx];
            }
            #pragma unroll
            for (int i = 0; i < 4; i++)
                #pragma unroll
                for (int j = 0; j < 4; j++) {
                    acc[i][j] = __builtin_amdgcn_mfma_f32_16x16x32_bf16(ah[i], bh[j], acc[i][j], 0, 0, 0);
                    acc[i][j] = __builtin_amdgcn_mfma_f32_16x16x32_bf16(ah[i], bl[j], acc[i][j], 0, 0, 0);
                    acc[i][j] = __builtin_amdgcn_mfma_f32_16x16x32_bf16(al[i], bh[j], acc[i][j], 0, 0, 0);
                }
        }
        __syncthreads();
    }

    #pragma unroll
    for (int i = 0; i < 4; i++)
        #pragma unroll
        for (int j = 0; j < 4; j++)
            #pragma unroll
            for (int r = 0; r < 4; r++) {
                int row = mBase + wr * 64 + i * 16 + quad * 4 + r;
                int col = nBase + wc * 64 + j * 16 + lr;
                float v = sigmoidf_(acc[i][j][r]);
                size_t idx = (size_t)(col >> 6) * NU + (size_t)row * 64 + (col & 63);
                __hip_bfloat16 h = __float2bfloat16(v);
                OutH[idx] = h;
                OutL[idx] = __float2bfloat16(v - __bfloat162float(h));
            }
}

// ---------------- SpMM: x1B += adj @ X (f32 adj vals, bf16 X rows) ----------------
// 1D XCD-pinned grid: wgid<4096: jt = wgid&7 (all blocks of a j-tile on ONE XCD ->
// its 2MB X column slice stays L2-resident), nb = wgid>>3. wgid>=4096: jt=8 (input cols).
// Block = 4 waves, wave-per-node. CSR metadata staged in LDS (broadcast reads, addresses
// available early); gather loop unrolled 8 for deep VMEM pipelining.
__global__ __launch_bounds__(256) void spmm_add(
    const __hip_bfloat16* __restrict__ X,
    const unsigned short* __restrict__ cols,
    const float* __restrict__ vals,
    const int* __restrict__ nnz,
    __hip_bfloat16* __restrict__ OutH,
    __hip_bfloat16* __restrict__ OutL)
{
    __shared__ unsigned short colS[4 * CAP];
    __shared__ float          valS[4 * CAP];
    __shared__ int            cntS[4];

    int tid  = threadIdx.x;
    int wave = tid >> 6, lane = tid & 63;
    int wgid = blockIdx.x;
    int jt, nb;
    if (wgid < 4096) { jt = wgid & 7; nb = wgid >> 3; }
    else             { jt = 8;        nb = wgid - 4096; }
    int nBase = nb * 4;

    // stage CSR metadata for the block's 4 nodes (contiguous in cols/vals)
    if (tid < 4) cntS[tid] = nnz[nBase + tid];
    {
        const unsigned short* cpg = cols + (size_t)nBase * CAP;
        const float*          vpg = vals + (size_t)nBase * CAP;
        #pragma unroll
        for (int it = 0; it < 3; it++) {
            int idx = tid + it * 256;
            colS[idx] = cpg[idx];
            valS[idx] = vpg[idx];
        }
    }
    __syncthreads();

    int n   = nBase + wave;
    int cnt = cntS[wave];
    const unsigned short* cp = colS + wave * CAP;
    const float*          vp = valS + wave * CAP;
    const short* Xs = (const short*)X;

    if (jt < 8) {
        int j0 = jt * 512 + lane * 8;
        float acc[8];
        #pragma unroll
        for (int e = 0; e < 8; e++) acc[e] = 0.f;
        int i = 0;
        for (; i + 8 <= cnt; i += 8) {
            int   c[8]; float a[8];
            #pragma unroll
            for (int q = 0; q < 8; q++) { c[q] = cp[i + q]; a[q] = vp[i + q]; }
            s16x8 xv[8];
            #pragma unroll
            for (int q = 0; q < 8; q++)
                xv[q] = *(const s16x8*)(Xs + (size_t)c[q] * XSTR + j0);
            #pragma unroll
            for (int q = 0; q < 8; q++)
                #pragma unroll
                for (int e = 0; e < 8; e++) acc[e] += a[q] * bfs2f(xv[q][e]);
        }
        for (; i < cnt; i++) {
            int c = cp[i]; float a = vp[i];
            s16x8 xv = *(const s16x8*)(Xs + (size_t)c * XSTR + j0);
            #pragma unroll
            for (int e = 0; e < 8; e++) acc[e] += a * bfs2f(xv[e]);
        }
        // blocked: j = jt*512 + lane*8 -> block = jt*8 + (lane>>3), u = (lane&7)*8
        size_t o = (size_t)(jt * 8 + (lane >> 3)) * NU + (size_t)n * 64 + (lane & 7) * 8;
        s16x8 h = *(const s16x8*)((const short*)OutH + o);
        s16x8 l = *(const s16x8*)((const short*)OutL + o);
        s16x8 nh, nl;
        #pragma unroll
        for (int e = 0; e < 8; e++) {
            float v = bfs2f(h[e]) + bfs2f(l[e]) + acc[e];
            short hh = f2bfs(v);
            nh[e] = hh;
            nl[e] = f2bfs(v - bfs2f(hh));
        }
        *(s16x8*)((short*)OutH + o) = nh;
        *(s16x8*)((short*)OutL + o) = nl;
    } else {
        float acc = 0.f;
        int i = 0;
        for (; i + 8 <= cnt; i += 8) {
            int   c[8]; float a[8];
            #pragma unroll
            for (int q = 0; q < 8; q++) { c[q] = cp[i + q]; a[q] = vp[i + q]; }
            short xv[8];
            #pragma unroll
            for (int q = 0; q < 8; q++) xv[q] = Xs[(size_t)c[q] * XSTR + 4096 + lane];
            #pragma unroll
            for (int q = 0; q < 8; q++) acc += a[q] * bfs2f(xv[q]);
        }
        for (; i < cnt; i++) {
            int c = cp[i]; float a = vp[i];
            acc += a * bfs2f(Xs[(size_t)c * XSTR + 4096 + lane]);
        }
        size_t o = (size_t)64 * NU + (size_t)n * 64 + lane;   // block 64, u = lane(=b)
        float v = bfs2f(((const short*)OutH)[o]) + bfs2f(((const short*)OutL)[o]) + acc;
        short hh = f2bfs(v);
        ((short*)OutH)[o] = hh;
        ((short*)OutL)[o] = f2bfs(v - bfs2f(hh));
    }
}

// ---------------- head1 (split MFMA): gates = x1s @ w0T + w0_row0*xin + b0 ----------------
// x1B blocked input: A-fragments loaded DIRECTLY from global (coalesced 64B segments).
// W fragments direct from global (L1-resident). LDS only for the x0sT transpose (XOR-swizzled).
// launch_bounds (256,3): VGPR cap 170 so the per-i state preloads batch into one load cluster.
__global__ __launch_bounds__(256, 3) void head1_mfma(
    const __hip_bfloat16* __restrict__ x1h, const __hip_bfloat16* __restrict__ x1l,
    const __hip_bfloat16* __restrict__ Wh, const __hip_bfloat16* __restrict__ Wl,
    const float* __restrict__ w0, const float* __restrict__ b0,
    const float* __restrict__ state,
    __hip_bfloat16* __restrict__ xh, __hip_bfloat16* __restrict__ xl,
    __hip_bfloat16* __restrict__ u_buf,
    __hip_bfloat16* __restrict__ Xout)
{
    __shared__ __align__(16) short trH[8192];   // [64 o][128 n], n XOR-swizzled by (o&15)<<3
    __shared__ __align__(16) short trL[8192];
    __shared__ float xinS[128];

    int n0 = blockIdx.x * 128;
    int b  = blockIdx.y;
    int tid = threadIdx.x;
    int wave = tid >> 6, lane = tid & 63;
    int quad = lane >> 4, lr = lane & 15;
    int wr = wave >> 1, wc = wave & 1;

    if (tid < 128) {
        size_t o = (size_t)64 * NU + (size_t)(n0 + tid) * 64 + b;
        xinS[tid] = __bfloat162float(x1h[o]) + __bfloat162float(x1l[o]);
    }

    f32x4 acc[4][4];
    #pragma unroll
    for (int i = 0; i < 4; i++)
        #pragma unroll
        for (int j = 0; j < 4; j++) { f32x4 z = {0.f,0.f,0.f,0.f}; acc[i][j] = z; }

    const short* Xh = (const short*)x1h + (size_t)b * NU;
    const short* Xl = (const short*)x1l + (size_t)b * NU;
    const short* Wh_ = (const short*)Wh;
    const short* Wl_ = (const short*)Wl;

    #pragma unroll
    for (int ks = 0; ks < 2; ks++) {
        s16x8 ah[4], al[4];
        #pragma unroll
        for (int i = 0; i < 4; i++) {
            size_t off = (size_t)(n0 + wr * 64 + i * 16 + lr) * 64 + ks * 32 + quad * 8;
            ah[i] = *(const s16x8*)(Xh + off);
            al[i] = *(const s16x8*)(Xl + off);
        }
        #pragma unroll
        for (int j = 0; j < 4; j++) {
            size_t wo = ((size_t)(ks * 4 + quad) * 128 + wc * 64 + j * 16 + lr) * 8;
            s16x8 bh = *(const s16x8*)(Wh_ + wo);
            s16x8 bl = *(const s16x8*)(Wl_ + wo);
            #pragma unroll
            for (int i = 0; i < 4; i++) {
                acc[i][j] = __builtin_amdgcn_mfma_f32_16x16x32_bf16(ah[i], bh, acc[i][j], 0, 0, 0);
                acc[i][j] = __builtin_amdgcn_mfma_f32_16x16x32_bf16(ah[i], bl, acc[i][j], 0, 0, 0);
                acc[i][j] = __builtin_amdgcn_mfma_f32_16x16x32_bf16(al[i], bh, acc[i][j], 0, 0, 0);
            }
        }
    }
    __syncthreads();   // xinS ready

    if (wc == 0) {
        #pragma unroll
        for (int i = 0; i < 4; i++) {
            // batched preload: 16 independent state loads in flight, then compute
            float sv[4][4];
            #pragma unroll
            for (int j = 0; j < 4; j++)
                #pragma unroll
                for (int r = 0; r < 4; r++)
                    sv[j][r] = state[(size_t)b * NU
                                     + (size_t)(n0 + wr * 64 + i * 16 + quad * 4 + r) * 64
                                     + j * 16 + lr];
            #pragma unroll
            for (int j = 0; j < 4; j++)
                #pragma unroll
                for (int r = 0; r < 4; r++) {
                    int n_loc = wr * 64 + i * 16 + quad * 4 + r;
                    int o = j * 16 + lr;
                    float g = acc[i][j][r] + w0[o] * xinS[n_loc] + b0[o];
                    float sg = sigmoidf_(g);
                    float rs = sg * sv[j][r];
                    short h = f2bfs(rs);
                    int sw = n_loc ^ ((o & 15) << 3);
                    trH[o * 128 + sw] = h;
                    trL[o * 128 + sw] = f2bfs(rs - bfs2f(h));
                    ((short*)Xout)[(size_t)(n0 + n_loc) * XSTR + b * 64 + o] = h;
                }
        }
    } else {
        #pragma unroll
        for (int i = 0; i < 4; i++)
            #pragma unroll
            for (int j = 0; j < 4; j++)
                #pragma unroll
                for (int r = 0; r < 4; r++) {
                    int n_loc = wr * 64 + i * 16 + quad * 4 + r;
                    int o = 64 + j * 16 + lr;
                    float g = acc[i][j][r] + w0[o] * xinS[n_loc] + b0[o];
                    float sg = sigmoidf_(g);
                    u_buf[(size_t)b * NU + (size_t)(n0 + n_loc) * 64 + (o - 64)] = __float2bfloat16(sg);
                }
    }
    __syncthreads();

    {
        int row = tid >> 2, seg = tid & 3;
        int xorv = (row & 15) << 3;
        short* dh = (short*)xh + (size_t)(b * 64 + row) * N_NODES + n0 + seg * 32;
        short* dl = (short*)xl + (size_t)(b * 64 + row) * N_NODES + n0 + seg * 32;
        #pragma unroll
        for (int q = 0; q < 4; q++) {
            int src = row * 128 + ((seg * 32 + q * 8) ^ xorv);
            *(uint4*)(dh + q * 8) = *(const uint4*)(trH + src);
            *(uint4*)(dl + q * 8) = *(const uint4*)(trL + src);
        }
    }
}

// ---------------- head2 (split MFMA): out = u*s + (1-u)*tanh(x1s@w1T + w1_row0*xin + b1) ----------------
// A-fragments + W fragments direct from global; no LDS except xinS.
// launch_bounds (256,3): room to batch ALL 32 state + 32 u_buf loads before the tanh loop.
__global__ __launch_bounds__(256, 3) void head2_mfma(
    const __hip_bfloat16* __restrict__ x1h, const __hip_bfloat16* __restrict__ x1l,
    const __hip_bfloat16* __restrict__ Wh, const __hip_bfloat16* __restrict__ Wl,
    const float* __restrict__ w1, const float* __restrict__ b1,
    const float* __restrict__ state, const __hip_bfloat16* __restrict__ u_buf,
    float* __restrict__ out)
{
    __shared__ float xinS[128];

    int n0 = blockIdx.x * 128;
    int b  = blockIdx.y;
    int tid = threadIdx.x;
    int wave = tid >> 6, lane = tid & 63;
    int quad = lane >> 4, lr = lane & 15;

    if (tid < 128) {
        size_t o = (size_t)64 * NU + (size_t)(n0 + tid) * 64 + b;
        xinS[tid] = __bfloat162float(x1h[o]) + __bfloat162float(x1l[o]);
    }

    f32x4 acc[2][4];
    #pragma unroll
    for (int i = 0; i < 2; i++)
        #pragma unroll
        for (int j = 0; j < 4; j++) { f32x4 z = {0.f,0.f,0.f,0.f}; acc[i][j] = z; }

    const short* Xh = (const short*)x1h + (size_t)b * NU;
    const short* Xl = (const short*)x1l + (size_t)b * NU;
    const short* Wh_ = (const short*)Wh;
    const short* Wl_ = (const short*)Wl;

    #pragma unroll
    for (int ks = 0; ks < 2; ks++) {
        s16x8 ah[2], al[2];
        #pragma unroll
        for (int i = 0; i < 2; i++) {
            size_t off = (size_t)(n0 + wave * 32 + i * 16 + lr) * 64 + ks * 32 + quad * 8;
            ah[i] = *(const s16x8*)(Xh + off);
            al[i] = *(const s16x8*)(Xl + off);
        }
        #pragma unroll
        for (int j = 0; j < 4; j++) {
            size_t wo = ((size_t)(ks * 4 + quad) * 64 + j * 16 + lr) * 8;
            s16x8 bh = *(const s16x8*)(Wh_ + wo);
            s16x8 bl = *(const s16x8*)(Wl_ + wo);
            #pragma unroll
            for (int i = 0; i < 2; i++) {
                acc[i][j] = __builtin_amdgcn_mfma_f32_16x16x32_bf16(ah[i], bh, acc[i][j], 0, 0, 0);
                acc[i][j] = __builtin_amdgcn_mfma_f32_16x16x32_bf16(ah[i], bl, acc[i][j], 0, 0, 0);
                acc[i][j] = __builtin_amdgcn_mfma_f32_16x16x32_bf16(al[i], bh, acc[i][j], 0, 0, 0);
            }
        }
    }
    __syncthreads();   // xinS ready

    // batched preload of state + u (64 independent loads in flight)
    float sv[2][4][4];
    float uv[2][4][4];
    #pragma unroll
    for (int i = 0; i < 2; i++)
        #pragma unroll
        for (int j = 0; j < 4; j++)
            #pragma unroll
            for (int r = 0; r < 4; r++) {
                size_t sidx = (size_t)b * NU
                            + (size_t)(n0 + wave * 32 + i * 16 + quad * 4 + r) * 64
                            + j * 16 + lr;
                sv[i][j][r] = state[sidx];
                uv[i][j][r] = __bfloat162float(u_buf[sidx]);
            }

    #pragma unroll
    for (int i = 0; i < 2; i++)
        #pragma unroll
        for (int j = 0; j < 4; j++)
            #pragma unroll
            for (int r = 0; r < 4; r++) {
                int n_loc = wave * 32 + i * 16 + quad * 4 + r;
                int o = j * 16 + lr;
                float g = acc[i][j][r] + w1[o] * xinS[n_loc] + b1[o];
                float c = tanhf(g);
                size_t sidx = (size_t)b * NU + (size_t)(n0 + n_loc) * 64 + o;
                float ug = uv[i][j][r];
                float svv = sv[i][j][r];
                out[sidx] = ug * svv + (1.0f - ug) * c;
            }
}

extern "C" void kernel_launch(void* const* d_in, const int* in_sizes, int n_in,
                              void* d_out, int out_size, void* d_ws, size_t ws_size,
                              hipStream_t stream)
{
    const float* inputs = (const float*)d_in[0];
    const float* state  = (const float*)d_in[1];
    const float* adj    = (const float*)d_in[2];
    // d_in[3] = adj1 : unused (discarded outfc path)
    const float* afc    = (const float*)d_in[4];   // [C][N]
    const float* afct   = (const float*)d_in[5];   // [N][C]
    const float* w0     = (const float*)d_in[6];
    const float* b0     = (const float*)d_in[7];
    const float* w1     = (const float*)d_in[8];
    const float* b1     = (const float*)d_in[9];
    // d_in[10..13]: unused

    float* out = (float*)d_out;

    char* p = (char*)d_ws;
    __hip_bfloat16* afc_h    = (__hip_bfloat16*)p; p += (size_t)C_NODES * N_NODES * 2;
    __hip_bfloat16* afc_l    = (__hip_bfloat16*)p; p += (size_t)C_NODES * N_NODES * 2;
    __hip_bfloat16* afct_h   = (__hip_bfloat16*)p; p += (size_t)N_NODES * C_NODES * 2;
    __hip_bfloat16* afct_l   = (__hip_bfloat16*)p; p += (size_t)N_NODES * C_NODES * 2;
    __hip_bfloat16* w0T_h    = (__hip_bfloat16*)p; p += 8192 * 2;
    __hip_bfloat16* w0T_l    = (__hip_bfloat16*)p; p += 8192 * 2;
    __hip_bfloat16* w1T_h    = (__hip_bfloat16*)p; p += 4096 * 2;
    __hip_bfloat16* w1T_l    = (__hip_bfloat16*)p; p += 4096 * 2;
    __hip_bfloat16* x0sT_h   = (__hip_bfloat16*)p; p += (size_t)JSX * N_NODES * 2;       // 17.3 MB
    __hip_bfloat16* x0sT_l   = (__hip_bfloat16*)p; p += (size_t)JSX * N_NODES * 2;
    __hip_bfloat16* x0fcT_h  = (__hip_bfloat16*)p; p += (size_t)JSX * C_NODES * 2;       // 2.16 MB
    __hip_bfloat16* x0fcT_l  = (__hip_bfloat16*)p; p += (size_t)JSX * C_NODES * 2;
    // part (ZSPLIT x JSX x 256 f32 = 34.6 MB) ALIASES x1B_h/x1B_l (34.6 MB):
    // part is live only gemm1->reduce; x1B is fully rewritten by gemm_coarse afterwards.
    float*          part     = (float*)p;
    __hip_bfloat16* x1B_h    = (__hip_bfloat16*)p; p += (size_t)66 * NU * 2;             // 17.3 MB (batch-blocked)
    __hip_bfloat16* x1B_l    = (__hip_bfloat16*)p; p += (size_t)66 * NU * 2;
    __hip_bfloat16* u_buf    = (__hip_bfloat16*)p; p += (size_t)BATCH * NU * 2;          // 16.78 MB
    __hip_bfloat16* X        = (__hip_bfloat16*)p; p += (size_t)N_NODES * XSTR * 2;      // 17.04 MB
    unsigned short* csr_cols = (unsigned short*)p; p += (size_t)N_NODES * CAP * 2;       // 0.79 MB
    float*          csr_vals = (float*)p;          p += (size_t)N_NODES * CAP * 4;       // 1.57 MB
    int*            csr_nnz  = (int*)p;            p += (size_t)N_NODES * 4;
    // total ~114 MB

    dim3 blk(256);

    // ---- once: converts + CSR + extended-row setup ----
    cvt_split<<<256,  blk, 0, stream>>>(afc,  afc_h,  afc_l,  C_NODES * N_NODES);
    cvt_split<<<256,  blk, 0, stream>>>(afct, afct_h, afct_l, N_NODES * C_NODES);
    cvt_w    <<<32,   blk, 0, stream>>>(w0, w1, w0T_h, w0T_l, w1T_h, w1T_l);
    setup_ext<<<128,  blk, 0, stream>>>(inputs, x0sT_h, x0sT_l, x0fcT_h, x0fcT_l, X);
    build_csr<<<512,  blk, 0, stream>>>(adj, csr_cols, csr_vals, csr_nnz);

    // ---- pass 1 ----
    build_x0sT<<<dim3(32, 64), blk, 0, stream>>>(state, x0sT_h, x0sT_l, X);
    gemm1_mfma128<<<dim3(2, 33, ZSPLIT), blk, 0, stream>>>(x0sT_h, x0sT_l, afc_h, afc_l, part);
    reduce_split<<<1024, blk, 0, stream>>>(part, x0fcT_h, x0fcT_l, NX * C_NODES);
    gemm_coarse<<<dim3(33, 16), blk, 0, stream>>>(afct_h, afct_l, x0fcT_h, x0fcT_l, x1B_h, x1B_l);
    spmm_add<<<dim3(4608), blk, 0, stream>>>(X, csr_cols, csr_vals, csr_nnz, x1B_h, x1B_l);
    head1_mfma<<<dim3(16, 64), blk, 0, stream>>>(x1B_h, x1B_l, w0T_h, w0T_l, w0, b0,
                                                 state, x0sT_h, x0sT_l, u_buf, X);

    // ---- pass 2 (x0sT/X state rows now hold r*state; input rows unchanged) ----
    gemm1_mfma128<<<dim3(2, 33, ZSPLIT), blk, 0, stream>>>(x0sT_h, x0sT_l, afc_h, afc_l, part);
    reduce_split<<<1024, blk, 0, stream>>>(part, x0fcT_h, x0fcT_l, NX * C_NODES);
    gemm_coarse<<<dim3(33, 16), blk, 0, stream>>>(afct_h, afct_l, x0fcT_h, x0fcT_l, x1B_h, x1B_l);
    spmm_add<<<dim3(4608), blk, 0, stream>>>(X, csr_cols, csr_vals, csr_nnz, x1B_h, x1B_l);
    head2_mfma<<<dim3(16, 64), blk, 0, stream>>>(x1B_h, x1B_l, w1T_h, w1T_l, w1, b1,
                                                 state, u_buf, out);
}